// Round 10
// baseline (560.286 us; speedup 1.0000x reference)
//
#include <hip/hip_runtime.h>
#include <cstdint>
#include <cstddef>

// ---------------------------------------------------------------------------
// CircularSplineLayer pipeline:
//  k_stats          global sum/sumsq of x_passive; also ldout = ldin (free)
//  k_prep           xn -> bf16 [1024][4096]
//  k_transpose_cvt  f32 [K][N] -> bf16 [N][K], 256x128 tiles, XOR-swizzled LDS
//  k_gemm1          split-K=2 MFMA bf16, 4-deep LDS ring + counted vmcnt
//  k_gemm1b         combine partials + bias + tanh -> h bf16 [1024][512]
//  k_gemm2          SAME 256x96 tile / staging / barriers as r8, but 512
//                   threads (8 waves): per-wave acc 96->48, unified regs
//                   ~180->~110 -> 4 waves/SIMD (16 waves/CU, 2 blocks/CU
//                   co-resident to cover the vmcnt(0) drains). Per-block
//                   traffic byte-identical to r8 (r4's tile-split regression
//                   avoided). T14 issue-early split. Atomic log-density;
//                   phi staged in LDS -> float4 coalesced stores.
// ---------------------------------------------------------------------------

typedef unsigned short u16;
typedef __bf16 bf16x8 __attribute__((ext_vector_type(8)));
typedef float f32x4 __attribute__((ext_vector_type(4)));
typedef unsigned short u16x8 __attribute__((ext_vector_type(8)));
typedef unsigned short u16x4 __attribute__((ext_vector_type(4)));
typedef unsigned short u16x2 __attribute__((ext_vector_type(2)));

#define TWOPI_F 6.28318530717958647692f

static __device__ __forceinline__ u16 f32_to_bf16(float f){
  unsigned u = __builtin_bit_cast(unsigned, f);
  return (u16)((u + 0x7fffu + ((u >> 16) & 1u)) >> 16);   // RNE
}
static __device__ __forceinline__ void async16(void* lds, const void* g){
  // global->LDS DMA, 16B/lane; LDS dest = wave-uniform base + lane*16
  __builtin_amdgcn_global_load_lds((const __attribute__((address_space(1))) void*)g,
                                   (__attribute__((address_space(3))) void*)lds,
                                   16, 0, 0);
}
static __device__ __forceinline__ float rcpf(float x){ return __builtin_amdgcn_rcpf(x); }
static __device__ __forceinline__ float fast_tanh(float x){
  x = fminf(fmaxf(x, -15.f), 15.f);
  float e = __expf(2.f * x);
  return (e - 1.f) / (e + 1.f);
}
// clamp-free tanh: 1 - 2/(e^{2x}+1); inf-safe (rcp(inf)=0 -> 1, rcp(1)=1 -> -1)
static __device__ __forceinline__ float tanh_nc(float x){
  const float e2 = __expf(2.f * x);
  return 1.f - 2.f * rcpf(e2 + 1.f);
}
// exp(tanh(x)) fused, clamp-free
static __device__ __forceinline__ float exp_tanh(float x){
  const float e2 = __expf(2.f * x);
  const float u  = rcpf(e2 + 1.f);
  return __expf(1.f - 2.f * u);
}

// ---- global sum / sumsq of x_passive (4194304 f32); ldout init piggyback ----
__global__ void k_stats(const float* __restrict__ xp, float* __restrict__ stats,
                        const float* __restrict__ ldin, float* __restrict__ ldout){
  __shared__ float ss[4], sq[4];
  const int tid = threadIdx.x;
  if (tid == 0) ldout[blockIdx.x] = ldin[blockIdx.x];    // 1024 blocks == B
  const long gt = (long)blockIdx.x * 256 + tid;          // float4 index
  const float4* x4 = (const float4*)xp;
  float s = 0.f, q = 0.f;
  #pragma unroll
  for (int p = 0; p < 4; ++p){
    float4 v = x4[gt + (long)p * 262144];
    s += v.x + v.y + v.z + v.w;
    q += v.x*v.x + v.y*v.y + v.z*v.z + v.w*v.w;
  }
  #pragma unroll
  for (int off = 32; off; off >>= 1){
    s += __shfl_down(s, off);
    q += __shfl_down(q, off);
  }
  if ((tid & 63) == 0){ ss[tid>>6] = s; sq[tid>>6] = q; }
  __syncthreads();
  if (tid == 0){
    atomicAdd(stats,     ss[0]+ss[1]+ss[2]+ss[3]);
    atomicAdd(stats + 1, sq[0]+sq[1]+sq[2]+sq[3]);
  }
}

// ---- xn = (x - mean)*istd -> bf16 ----
__global__ void k_prep(const float* __restrict__ xp, const float* __restrict__ stats,
                       u16* __restrict__ xn){
  const long t = (long)blockIdx.x * 256 + threadIdx.x;   // 524288 threads, 8 elems each
  const float sum = stats[0], sq = stats[1];
  const float N = 4194304.f;
  const float mean = sum / N;
  const float istd = rsqrtf((sq - sum*sum/N) / (N - 1.f));  // ddof=1
  const float4* x4 = (const float4*)xp;
  const float4 a = x4[2*t], b = x4[2*t+1];
  u16x8 o;
  o[0]=f32_to_bf16((a.x-mean)*istd); o[1]=f32_to_bf16((a.y-mean)*istd);
  o[2]=f32_to_bf16((a.z-mean)*istd); o[3]=f32_to_bf16((a.w-mean)*istd);
  o[4]=f32_to_bf16((b.x-mean)*istd); o[5]=f32_to_bf16((b.y-mean)*istd);
  o[6]=f32_to_bf16((b.z-mean)*istd); o[7]=f32_to_bf16((b.w-mean)*istd);
  ((u16x8*)xn)[t] = o;
}

// ---- f32 [Kd][Nd] -> bf16 [Nd][Kd]; 256(k) x 128(n) tiles ----
// Store: k-pair P of row n lands at pair-position P ^ (sigma<<2), sigma=(n>>2)&7
// (an XOR on the pair-GROUP index P>>2). Read: pair-group lk is therefore at
// group-position lk ^ sigma. Global reads AND writes stay 512B-contiguous.
__global__ __launch_bounds__(256) void k_transpose_cvt(const float* __restrict__ in,
                                                       u16* __restrict__ out,
                                                       int Kd, int Nd){
  __shared__ __align__(16) u16 tT[128*256];
  const int tid = threadIdx.x;
  const long k0 = (long)blockIdx.x * 256, n0 = (long)blockIdx.y * 128;
  const int lam = tid & 31, g = tid >> 5;
  const int c = lam * 4;
  const int sig = (lam & 7) << 2;                 // (sigma)<<2, sigma=(n>>2)&7
  #pragma unroll
  for (int pass = 0; pass < 16; ++pass){
    const int P = pass*8 + g;                     // k-pair index 0..127
    const float4 f0 = *(const float4*)&in[(k0 + 2*P    )*Nd + n0 + c];
    const float4 f1 = *(const float4*)&in[(k0 + 2*P + 1)*Nd + n0 + c];
    const int pp = 2*(P ^ sig);
    *(u16x2*)&tT[(c    )*256 + pp] = u16x2{f32_to_bf16(f0.x), f32_to_bf16(f1.x)};
    *(u16x2*)&tT[(c + 1)*256 + pp] = u16x2{f32_to_bf16(f0.y), f32_to_bf16(f1.y)};
    *(u16x2*)&tT[(c + 2)*256 + pp] = u16x2{f32_to_bf16(f0.z), f32_to_bf16(f1.z)};
    *(u16x2*)&tT[(c + 3)*256 + pp] = u16x2{f32_to_bf16(f0.w), f32_to_bf16(f1.w)};
  }
  __syncthreads();
  const int w = tid >> 6, l = tid & 63;
  const int lh = l >> 5, lk = l & 31;
  #pragma unroll
  for (int it = 0; it < 16; ++it){
    const int n = (w << 5) + (it << 1) + lh;
    const int s2 = (n >> 2) & 7;                  // sigma (group-index XOR) — NOT <<2
    const u16x8 v = *(const u16x8*)&tT[n*256 + 8*(lk ^ s2)];
    *(u16x8*)&out[(n0 + n)*Kd + k0 + 8*lk] = v;
  }
}

// ---- GEMM1 split-K: partial = xn @ w1 over half of K. M=1024 N=512 ----
// 4-deep LDS ring, prefetch depth 2, counted vmcnt (2 DMA instrs/wave/stage).
__global__ __launch_bounds__(256, 2) void k_gemm1(
    const u16* __restrict__ xn,   // [1024][4096] bf16
    const u16* __restrict__ w1t,  // [512][4096] bf16 (n-major)
    float* __restrict__ pp)       // [2][1024][512] f32 partials
{
  __shared__ __align__(16) u16 sA[4][64*32];
  __shared__ __align__(16) u16 sB[4][64*32];
  const int tid = threadIdx.x, lane = tid & 63, w = tid >> 6;
  const int n0 = blockIdx.x << 6, m0 = blockIdx.y << 6;
  const int ks = blockIdx.z;
  const int wm = w >> 1, wn = w & 1;
  const int rA = lane >> 2, cA = (lane & 3) << 3;
  const int fr = lane & 15, fq = lane >> 4;
  const f32x4 z4 = {0.f, 0.f, 0.f, 0.f};
  f32x4 acc[2][2];
  #pragma unroll
  for (int i=0;i<2;i++){ acc[i][0] = z4; acc[i][1] = z4; }

  auto stage = [&](int kt){
    const int b = kt & 3;
    const int kofs = (ks << 11) + (kt << 5) + cA;
    async16(sA[b] + w*512, xn  + (long)(m0 + w*16 + rA)*4096 + kofs);
    async16(sB[b] + w*512, w1t + (long)(n0 + w*16 + rA)*4096 + kofs);
  };

  stage(0); stage(1);
  for (int kt = 0; kt < 64; ++kt){
    if (kt < 62){
      stage(kt + 2);
      asm volatile("s_waitcnt vmcnt(4)" ::: "memory");   // kt's 2 DMAs done
    } else if (kt == 62){
      asm volatile("s_waitcnt vmcnt(2)" ::: "memory");
    } else {
      asm volatile("s_waitcnt vmcnt(0)" ::: "memory");
    }
    __builtin_amdgcn_s_barrier();
    const int b = kt & 3;
    bf16x8 af[2], bfv[2];
    #pragma unroll
    for (int i=0;i<2;i++) af[i]  = *(const bf16x8*)(sA[b] + ((wm<<5) + i*16 + fr)*32 + (fq<<3));
    #pragma unroll
    for (int j=0;j<2;j++) bfv[j] = *(const bf16x8*)(sB[b] + ((wn<<5) + j*16 + fr)*32 + (fq<<3));
    #pragma unroll
    for (int i=0;i<2;i++)
      #pragma unroll
      for (int j=0;j<2;j++)
        acc[i][j] = __builtin_amdgcn_mfma_f32_16x16x32_bf16(af[i], bfv[j], acc[i][j], 0, 0, 0);
  }
  float* po = pp + ((size_t)ks << 19);
  #pragma unroll
  for (int i=0;i<2;i++)
    #pragma unroll
    for (int j=0;j<2;j++)
      #pragma unroll
      for (int r=0;r<4;r++){
        const int row = m0 + (wm<<5) + i*16 + (fq<<2) + r;   // C/D: row=(lane>>4)*4+reg
        const int col = n0 + (wn<<5) + j*16 + fr;            //      col=lane&15
        po[row*512 + col] = acc[i][j][r];
      }
}

// ---- combine split-K partials: h = tanh(p0+p1+b1) -> bf16 ----
__global__ void k_gemm1b(const float* __restrict__ pp, const float* __restrict__ b1,
                         u16* __restrict__ hb){
  const int t = blockIdx.x * 256 + threadIdx.x;    // 131072 float4 groups
  const float4 a = ((const float4*)pp)[t];
  const float4 b = ((const float4*)pp)[131072 + t];
  const float4 bb = ((const float4*)b1)[t & 127];
  u16x4 o;
  o[0] = f32_to_bf16(fast_tanh(a.x + b.x + bb.x));
  o[1] = f32_to_bf16(fast_tanh(a.y + b.y + bb.y));
  o[2] = f32_to_bf16(fast_tanh(a.z + b.z + bb.z));
  o[3] = f32_to_bf16(fast_tanh(a.w + b.w + bb.w));
  ((u16x4*)hb)[t] = o;
}

// ---- GEMM2 + spline epilogue: M=1024 N=98304 K=512, tile 256x96 ----
// 512 threads / 8 waves, grid 4096, bijective XCD-chunked swizzle.
// Per-block staging/barriers/traffic byte-identical to the 4-wave r8 build;
// each wave owns 32 output rows -> acc[2][6]=48 AGPR + ~60 arch VGPR
// => ~110 unified => 4 waves/SIMD (16 waves/CU, 2 blocks co-resident).
// T14 per-kt async split:
//   vmcnt(0)+barrier / ds_read+lgkm+sched_barrier+barrier / stage(kt+1) / MFMA
__global__ __launch_bounds__(512, 4) void k_gemm2(
    const u16* __restrict__ hmat,   // [1024][512] bf16
    const u16* __restrict__ w2t,    // [98304][512] bf16 (n-major)
    const float* __restrict__ b2,
    const float* __restrict__ x_in, // [1024][4096]
    const float* __restrict__ phase,
    float* __restrict__ phi_out,    // [1024][4096]
    float* __restrict__ ld)         // [1024] log-density accumulator (pre-init = ldin)
{
  __shared__ __align__(16) char smem[51200];
  u16* sA = (u16*)smem;              // [256][32] bf16 staging (16384 B)
  u16* sB = (u16*)(smem + 16384);    // [128][32] bf16 (rows >=96 are pad)
  float* sC = (float*)smem;          // [8 waves][16 rows][100] epilogue (51200 B)

  const int tid  = threadIdx.x;
  const int lane = tid & 63;
  const int w    = tid >> 6;                      // 0..7
  const int id   = blockIdx.x;
  const int work = ((id & 7) << 9) | (id >> 3);   // bijective, 4096 = 8*512
  const int m0   = (work & 3) << 8;               // 0,256,512,768
  const int nt   = work >> 2;                     // 0..1023
  const long n0  = (long)nt * 96;

  const int rA = lane >> 2, cA = (lane & 3) << 3;
  const int fr = lane & 15, fq = lane >> 4;

  const f32x4 z4 = {0.f, 0.f, 0.f, 0.f};
  f32x4 acc[2][6];
  #pragma unroll
  for (int i=0;i<2;i++)
    #pragma unroll
    for (int j=0;j<6;j++) acc[i][j] = z4;

  auto stage = [&](int kt){
    const int kofs = (kt << 5) + cA;
    #pragma unroll
    for (int cc = 0; cc < 2; ++cc){
      const int c = (w << 1) + cc;                         // 16 A chunks over 8 waves
      async16(sA + c*512, hmat + (long)(m0 + c*16 + rA)*512 + kofs);
    }
    {
      const int ch = w;                                    // 8 B chunks, 1 per wave
      int row = ch*16 + rA; if (row > 95) row = 95;        // clamp into valid rows
      async16(sB + ch*512, w2t + (n0 + row)*512 + kofs);
    }
  };

  stage(0);
  for (int kt = 0; kt < 16; ++kt){
    asm volatile("s_waitcnt vmcnt(0)" ::: "memory");       // own DMA(kt) done
    __builtin_amdgcn_s_barrier();                          // -> all waves' DMA done
    bf16x8 af[2], bfv[6];
    #pragma unroll
    for (int i=0;i<2;i++)
      af[i] = *(const bf16x8*)(sA + ((w<<5) + i*16 + fr)*32 + (fq<<3));
    #pragma unroll
    for (int j=0;j<6;j++)
      bfv[j] = *(const bf16x8*)(sB + (j*16 + fr)*32 + (fq<<3));
    asm volatile("s_waitcnt lgkmcnt(0)" ::: "memory");     // own ds_reads landed
    __builtin_amdgcn_sched_barrier(0);                     // rule #18 fence
    __builtin_amdgcn_s_barrier();                          // -> LDS reusable
    if (kt < 15) stage(kt + 1);                            // DMA flies under MFMA
    __builtin_amdgcn_sched_barrier(0);                     // keep issue before MFMA
    #pragma unroll
    for (int i=0;i<2;i++)
      #pragma unroll
      for (int j=0;j<6;j++)
        acc[i][j] = __builtin_amdgcn_mfma_f32_16x16x32_bf16(af[i], bfv[j], acc[i][j], 0, 0, 0);
  }
  // barrier #2 of kt=15 guarantees every wave's LDS reads are done -> sC reuse safe

  // ---- epilogue: RAW acc+b2 -> LDS -> per-(b,s_out) spline ----
  // myC regions are wave-private (8 x 6400 B). Each wave owns 32 rows =
  // 2 sixteen-row quarters (q = acc row-frag index). Three-pass register-diet
  // spline (r9). phi staged in cols 96..99 -> float4 coalesced stores.
  const float shift = phase[0];
  float b2c[6];
  #pragma unroll
  for (int j=0;j<6;j++) b2c[j] = b2[n0 + j*16 + fr];
  float* myC = sC + w*1600;                                // 16 rows x 100 floats

  #pragma unroll
  for (int q = 0; q < 2; ++q){                             // quarter = row-frag index
    #pragma unroll
    for (int j=0;j<6;j++)
      #pragma unroll
      for (int r=0;r<4;r++)
        myC[((fq<<2)+r)*100 + j*16 + fr] = acc[q][j][r] + b2c[j];

    const int row = fr;                 // 0..15 within quarter
    const int g   = fq;                 // s_out group 0..3
    const float* tp = myC + row*100 + g*24;

    const int bg = m0 + (w<<5) + (q<<4) + row;
    const int s  = (nt<<2) + g;
    const float x = x_in[(long)bg*4096 + s];

    // pass 1: w_raw = tp[8..15]; sw (no array kept)
    const f32x4 w0 = *(const f32x4*)(tp + 8);
    const f32x4 w1 = *(const f32x4*)(tp + 12);
    float sw = 0.f;
    #pragma unroll
    for (int i=0;i<4;i++){ sw += exp_tanh(w0[i]); sw += exp_tanh(w1[i]); }

    // bin search in RAW cumsum space: cum_norm < x  <=>  cum_raw < x*sw/2pi
    const float xs = x * sw * (1.f / TWOPI_F);

    // pass 2: recompute ew, capture k / wkr / xkr by monotone overwrite
    float cw = 0.f, wkr = 0.f, xkr = 0.f; int k = 0;
    #pragma unroll
    for (int i=0;i<8;i++){
      const float e = exp_tanh(i < 4 ? w0[i] : w1[i-4]);
      if (cw < xs || i == 0){ k = i; wkr = e; xkr = cw; }
      cw += e;
    }

    // pass 3: h_raw = tp[0..7]; capture hkr / phr at i==k
    const f32x4 h0 = *(const f32x4*)(tp);
    const f32x4 h1 = *(const f32x4*)(tp + 4);
    float h2 = 0.f, hkr = 0.f, phr = 0.f;
    #pragma unroll
    for (int i=0;i<8;i++){
      const float e = exp_tanh(i < 4 ? h0[i] : h1[i-4]);
      if (i == k){ hkr = e; phr = h2; }
      h2 += e;
    }
    const float sh = h2;

    // only the 2 selected d values get tanh+softplus (runtime-indexed LDS read)
    const float* dp = tp + 16;
    const float th0 = tanh_nc(dp[k]);
    const float th1 = tanh_nc(dp[(k + 1) & 7]);
    const float dk  = __logf(1.f + __expf(th0));   // softplus, arg in (-1,1)
    const float dk1 = __logf(1.f + __expf(th1));

    const float rsh = rcpf(sh);
    const float rwk = rcpf(wkr);
    const float alpha = (xs - xkr) * rwk;          // == (x - x_{k-1})/w_k
    const float sk = hkr * rwk * (sw * rsh);       // == h_k/w_k
    const float hk = TWOPI_F * hkr * rsh;
    const float ph = TWOPI_F * phr * rsh;
    const float a1m = alpha * (1.f - alpha);
    const float denom = sk + (dk1 + dk - 2.f*sk)*a1m;
    const float rd = rcpf(denom);
    const float phiv = ph + hk*(sk*alpha*alpha + dk*a1m)*rd;
    float p = phiv + shift;                 // conditional subtract == mod
    if (p >= TWOPI_F) p -= TWOPI_F;
    if (p >= TWOPI_F) p -= TWOPI_F;
    myC[row*100 + 96 + g] = p;              // stage phi (cols 96..99 free)

    const float om = 1.f - alpha;
    const float num = dk1*alpha*alpha + 2.f*sk*a1m + dk*om*om;
    const float srd = sk * rd;
    float lg = __logf(srd*srd*num);         // == log(sk^2*num/denom^2)
    lg += __shfl_xor(lg, 16);               // sum over the 4 s_out groups (same row)
    lg += __shfl_xor(lg, 32);
    if (lane < 16){
      atomicAdd(ld + bg, -lg);              // device-scope, fire-and-forget
      const f32x4 pv = *(const f32x4*)(myC + lane*100 + 96);   // row = lane (==fr)
      const int bgr = m0 + (w<<5) + (q<<4) + lane;
      float4 o; o.x = pv[0]; o.y = pv[1]; o.z = pv[2]; o.w = pv[3];
      *(float4*)&phi_out[(long)bgr*4096 + (nt<<2)] = o;        // 16B coalesced
    }
  }
}

extern "C" void kernel_launch(void* const* d_in, const int* in_sizes, int n_in,
                              void* d_out, int out_size, void* d_ws, size_t ws_size,
                              hipStream_t stream){
  (void)in_sizes; (void)n_in; (void)out_size; (void)ws_size;
  const float* x_in  = (const float*)d_in[0];
  const float* x_pas = (const float*)d_in[1];
  const float* ldin  = (const float*)d_in[2];
  const float* w1    = (const float*)d_in[3];
  const float* b1    = (const float*)d_in[4];
  const float* w2    = (const float*)d_in[5];
  const float* b2    = (const float*)d_in[6];
  const float* phase = (const float*)d_in[7];
  float* out   = (float*)d_out;
  float* phi   = out;
  float* ldout = out + (size_t)1024*4096;

  // workspace layout (needs ~118.5 MB)
  char* ws = (char*)d_ws;
  float* stats = (float*)ws;                       // 8 B
  u16* xn   = (u16*)(ws + 256);                    // 8 MB   [1024][4096] bf16
  u16* w1t  = (u16*)(ws + 8388864);                // 4 MB   [512][4096] bf16
  u16* hb   = (u16*)(ws + 12583168);               // 1 MB   [1024][512] bf16
  u16* w2t  = (u16*)(ws + 13631744);               // 96 MB  [98304][512] bf16
  float* part = (float*)(ws + 114295040);          // 4 MB   gemm1 split-K partials

  hipMemsetAsync(stats, 0, 8, stream);
  k_stats<<<1024, 256, 0, stream>>>(x_pas, stats, ldin, ldout);
  k_prep<<<2048, 256, 0, stream>>>(x_pas, stats, xn);
  k_transpose_cvt<<<dim3(16, 4),  256, 0, stream>>>(w1, w1t, 4096, 512);
  k_transpose_cvt<<<dim3(2, 768), 256, 0, stream>>>(w2, w2t, 512, 98304);
  k_gemm1<<<dim3(8, 16, 2), 256, 0, stream>>>(xn, w1t, part);
  k_gemm1b<<<512, 256, 0, stream>>>(part, b1, hb);
  k_gemm2<<<dim3(4096), 512, 0, stream>>>(hb, w2t, b2, x_in, phase, phi, ldout);
}

// Round 11
// 551.126 us; speedup vs baseline: 1.0166x; 1.0166x over previous
//
#include <hip/hip_runtime.h>
#include <cstdint>
#include <cstddef>

// ---------------------------------------------------------------------------
// CircularSplineLayer pipeline:
//  k_stats          global sum/sumsq of x_passive; also ldout = ldin (free)
//  k_prep           xn -> bf16 [1024][4096]
//  k_transpose_cvt  f32 [K][N] -> bf16 [N][K], 256x128 tiles, XOR-swizzled LDS
//  k_gemm1          split-K=2 MFMA bf16, 4-deep LDS ring + counted vmcnt
//  k_gemm1b         combine partials + bias + tanh -> h bf16 [1024][512]
//  k_gemm2          256x96 tile, 4 waves, BK=64 TWO-PLANE single buffer:
//                   8 K-steps of 48 MFMA/wave instead of 16 of 24 -> half the
//                   vmcnt(0) drains + barriers (the measured bottleneck:
//                   r10 proved occupancy is NOT binding; r8's per-kt chain
//                   amortization is). Each plane keeps r8's bank-floor
//                   layout. T14 issue-early split. Atomic log-density; phi
//                   staged in LDS -> float4 coalesced stores.
// ---------------------------------------------------------------------------

typedef unsigned short u16;
typedef __bf16 bf16x8 __attribute__((ext_vector_type(8)));
typedef float f32x4 __attribute__((ext_vector_type(4)));
typedef unsigned short u16x8 __attribute__((ext_vector_type(8)));
typedef unsigned short u16x4 __attribute__((ext_vector_type(4)));
typedef unsigned short u16x2 __attribute__((ext_vector_type(2)));

#define TWOPI_F 6.28318530717958647692f

static __device__ __forceinline__ u16 f32_to_bf16(float f){
  unsigned u = __builtin_bit_cast(unsigned, f);
  return (u16)((u + 0x7fffu + ((u >> 16) & 1u)) >> 16);   // RNE
}
static __device__ __forceinline__ void async16(void* lds, const void* g){
  // global->LDS DMA, 16B/lane; LDS dest = wave-uniform base + lane*16
  __builtin_amdgcn_global_load_lds((const __attribute__((address_space(1))) void*)g,
                                   (__attribute__((address_space(3))) void*)lds,
                                   16, 0, 0);
}
static __device__ __forceinline__ float rcpf(float x){ return __builtin_amdgcn_rcpf(x); }
static __device__ __forceinline__ float fast_tanh(float x){
  x = fminf(fmaxf(x, -15.f), 15.f);
  float e = __expf(2.f * x);
  return (e - 1.f) / (e + 1.f);
}
// clamp-free tanh: 1 - 2/(e^{2x}+1); inf-safe (rcp(inf)=0 -> 1, rcp(1)=1 -> -1)
static __device__ __forceinline__ float tanh_nc(float x){
  const float e2 = __expf(2.f * x);
  return 1.f - 2.f * rcpf(e2 + 1.f);
}
// exp(tanh(x)) fused, clamp-free
static __device__ __forceinline__ float exp_tanh(float x){
  const float e2 = __expf(2.f * x);
  const float u  = rcpf(e2 + 1.f);
  return __expf(1.f - 2.f * u);
}

// ---- global sum / sumsq of x_passive (4194304 f32); ldout init piggyback ----
__global__ void k_stats(const float* __restrict__ xp, float* __restrict__ stats,
                        const float* __restrict__ ldin, float* __restrict__ ldout){
  __shared__ float ss[4], sq[4];
  const int tid = threadIdx.x;
  if (tid == 0) ldout[blockIdx.x] = ldin[blockIdx.x];    // 1024 blocks == B
  const long gt = (long)blockIdx.x * 256 + tid;          // float4 index
  const float4* x4 = (const float4*)xp;
  float s = 0.f, q = 0.f;
  #pragma unroll
  for (int p = 0; p < 4; ++p){
    float4 v = x4[gt + (long)p * 262144];
    s += v.x + v.y + v.z + v.w;
    q += v.x*v.x + v.y*v.y + v.z*v.z + v.w*v.w;
  }
  #pragma unroll
  for (int off = 32; off; off >>= 1){
    s += __shfl_down(s, off);
    q += __shfl_down(q, off);
  }
  if ((tid & 63) == 0){ ss[tid>>6] = s; sq[tid>>6] = q; }
  __syncthreads();
  if (tid == 0){
    atomicAdd(stats,     ss[0]+ss[1]+ss[2]+ss[3]);
    atomicAdd(stats + 1, sq[0]+sq[1]+sq[2]+sq[3]);
  }
}

// ---- xn = (x - mean)*istd -> bf16 ----
__global__ void k_prep(const float* __restrict__ xp, const float* __restrict__ stats,
                       u16* __restrict__ xn){
  const long t = (long)blockIdx.x * 256 + threadIdx.x;   // 524288 threads, 8 elems each
  const float sum = stats[0], sq = stats[1];
  const float N = 4194304.f;
  const float mean = sum / N;
  const float istd = rsqrtf((sq - sum*sum/N) / (N - 1.f));  // ddof=1
  const float4* x4 = (const float4*)xp;
  const float4 a = x4[2*t], b = x4[2*t+1];
  u16x8 o;
  o[0]=f32_to_bf16((a.x-mean)*istd); o[1]=f32_to_bf16((a.y-mean)*istd);
  o[2]=f32_to_bf16((a.z-mean)*istd); o[3]=f32_to_bf16((a.w-mean)*istd);
  o[4]=f32_to_bf16((b.x-mean)*istd); o[5]=f32_to_bf16((b.y-mean)*istd);
  o[6]=f32_to_bf16((b.z-mean)*istd); o[7]=f32_to_bf16((b.w-mean)*istd);
  ((u16x8*)xn)[t] = o;
}

// ---- f32 [Kd][Nd] -> bf16 [Nd][Kd]; 256(k) x 128(n) tiles ----
// Store: k-pair P of row n lands at pair-position P ^ (sigma<<2), sigma=(n>>2)&7
// (an XOR on the pair-GROUP index P>>2). Read: pair-group lk is therefore at
// group-position lk ^ sigma. Global reads AND writes stay 512B-contiguous.
__global__ __launch_bounds__(256) void k_transpose_cvt(const float* __restrict__ in,
                                                       u16* __restrict__ out,
                                                       int Kd, int Nd){
  __shared__ __align__(16) u16 tT[128*256];
  const int tid = threadIdx.x;
  const long k0 = (long)blockIdx.x * 256, n0 = (long)blockIdx.y * 128;
  const int lam = tid & 31, g = tid >> 5;
  const int c = lam * 4;
  const int sig = (lam & 7) << 2;                 // (sigma)<<2, sigma=(n>>2)&7
  #pragma unroll
  for (int pass = 0; pass < 16; ++pass){
    const int P = pass*8 + g;                     // k-pair index 0..127
    const float4 f0 = *(const float4*)&in[(k0 + 2*P    )*Nd + n0 + c];
    const float4 f1 = *(const float4*)&in[(k0 + 2*P + 1)*Nd + n0 + c];
    const int pp = 2*(P ^ sig);
    *(u16x2*)&tT[(c    )*256 + pp] = u16x2{f32_to_bf16(f0.x), f32_to_bf16(f1.x)};
    *(u16x2*)&tT[(c + 1)*256 + pp] = u16x2{f32_to_bf16(f0.y), f32_to_bf16(f1.y)};
    *(u16x2*)&tT[(c + 2)*256 + pp] = u16x2{f32_to_bf16(f0.z), f32_to_bf16(f1.z)};
    *(u16x2*)&tT[(c + 3)*256 + pp] = u16x2{f32_to_bf16(f0.w), f32_to_bf16(f1.w)};
  }
  __syncthreads();
  const int w = tid >> 6, l = tid & 63;
  const int lh = l >> 5, lk = l & 31;
  #pragma unroll
  for (int it = 0; it < 16; ++it){
    const int n = (w << 5) + (it << 1) + lh;
    const int s2 = (n >> 2) & 7;                  // sigma (group-index XOR) — NOT <<2
    const u16x8 v = *(const u16x8*)&tT[n*256 + 8*(lk ^ s2)];
    *(u16x8*)&out[(n0 + n)*Kd + k0 + 8*lk] = v;
  }
}

// ---- GEMM1 split-K: partial = xn @ w1 over half of K. M=1024 N=512 ----
// 4-deep LDS ring, prefetch depth 2, counted vmcnt (2 DMA instrs/wave/stage).
__global__ __launch_bounds__(256, 2) void k_gemm1(
    const u16* __restrict__ xn,   // [1024][4096] bf16
    const u16* __restrict__ w1t,  // [512][4096] bf16 (n-major)
    float* __restrict__ pp)       // [2][1024][512] f32 partials
{
  __shared__ __align__(16) u16 sA[4][64*32];
  __shared__ __align__(16) u16 sB[4][64*32];
  const int tid = threadIdx.x, lane = tid & 63, w = tid >> 6;
  const int n0 = blockIdx.x << 6, m0 = blockIdx.y << 6;
  const int ks = blockIdx.z;
  const int wm = w >> 1, wn = w & 1;
  const int rA = lane >> 2, cA = (lane & 3) << 3;
  const int fr = lane & 15, fq = lane >> 4;
  const f32x4 z4 = {0.f, 0.f, 0.f, 0.f};
  f32x4 acc[2][2];
  #pragma unroll
  for (int i=0;i<2;i++){ acc[i][0] = z4; acc[i][1] = z4; }

  auto stage = [&](int kt){
    const int b = kt & 3;
    const int kofs = (ks << 11) + (kt << 5) + cA;
    async16(sA[b] + w*512, xn  + (long)(m0 + w*16 + rA)*4096 + kofs);
    async16(sB[b] + w*512, w1t + (long)(n0 + w*16 + rA)*4096 + kofs);
  };

  stage(0); stage(1);
  for (int kt = 0; kt < 64; ++kt){
    if (kt < 62){
      stage(kt + 2);
      asm volatile("s_waitcnt vmcnt(4)" ::: "memory");   // kt's 2 DMAs done
    } else if (kt == 62){
      asm volatile("s_waitcnt vmcnt(2)" ::: "memory");
    } else {
      asm volatile("s_waitcnt vmcnt(0)" ::: "memory");
    }
    __builtin_amdgcn_s_barrier();
    const int b = kt & 3;
    bf16x8 af[2], bfv[2];
    #pragma unroll
    for (int i=0;i<2;i++) af[i]  = *(const bf16x8*)(sA[b] + ((wm<<5) + i*16 + fr)*32 + (fq<<3));
    #pragma unroll
    for (int j=0;j<2;j++) bfv[j] = *(const bf16x8*)(sB[b] + ((wn<<5) + j*16 + fr)*32 + (fq<<3));
    #pragma unroll
    for (int i=0;i<2;i++)
      #pragma unroll
      for (int j=0;j<2;j++)
        acc[i][j] = __builtin_amdgcn_mfma_f32_16x16x32_bf16(af[i], bfv[j], acc[i][j], 0, 0, 0);
  }
  float* po = pp + ((size_t)ks << 19);
  #pragma unroll
  for (int i=0;i<2;i++)
    #pragma unroll
    for (int j=0;j<2;j++)
      #pragma unroll
      for (int r=0;r<4;r++){
        const int row = m0 + (wm<<5) + i*16 + (fq<<2) + r;   // C/D: row=(lane>>4)*4+reg
        const int col = n0 + (wn<<5) + j*16 + fr;            //      col=lane&15
        po[row*512 + col] = acc[i][j][r];
      }
}

// ---- combine split-K partials: h = tanh(p0+p1+b1) -> bf16 ----
__global__ void k_gemm1b(const float* __restrict__ pp, const float* __restrict__ b1,
                         u16* __restrict__ hb){
  const int t = blockIdx.x * 256 + threadIdx.x;    // 131072 float4 groups
  const float4 a = ((const float4*)pp)[t];
  const float4 b = ((const float4*)pp)[131072 + t];
  const float4 bb = ((const float4*)b1)[t & 127];
  u16x4 o;
  o[0] = f32_to_bf16(fast_tanh(a.x + b.x + bb.x));
  o[1] = f32_to_bf16(fast_tanh(a.y + b.y + bb.y));
  o[2] = f32_to_bf16(fast_tanh(a.z + b.z + bb.z));
  o[3] = f32_to_bf16(fast_tanh(a.w + b.w + bb.w));
  ((u16x4*)hb)[t] = o;
}

// ---- GEMM2 + spline epilogue: M=1024 N=98304 K=512, tile 256x96 ----
// 1-D grid 4096, bijective XCD-chunked swizzle: work = ((id&7)<<9)|(id>>3).
// BK=64 two-plane single buffer: plane h holds k-half h with r8's exact
// [row][32] bank-floor layout. 8 K-steps x 48 MFMA/wave; drains 16->8,
// barriers 32->16 (r10 proved occupancy non-binding; amortization is).
// Unified regs ~200 stays in the 129-256 allocation bucket -> occupancy
// unchanged vs r8. T14 issue-early split per step:
//   vmcnt(0)+barrier / ds_read 20 frags+lgkm+sched_barrier+barrier /
//   stage(s+1) (12 DMA fly under MFMA) / 48 MFMA
__global__ __launch_bounds__(256, 2) void k_gemm2(
    const u16* __restrict__ hmat,   // [1024][512] bf16
    const u16* __restrict__ w2t,    // [98304][512] bf16 (n-major)
    const float* __restrict__ b2,
    const float* __restrict__ x_in, // [1024][4096]
    const float* __restrict__ phase,
    float* __restrict__ phi_out,    // [1024][4096]
    float* __restrict__ ld)         // [1024] log-density accumulator (pre-init = ldin)
{
  __shared__ __align__(16) char smem[49152];
  u16* sA = (u16*)smem;              // 2 planes x [256][32] bf16 (2 x 16384 B)
  u16* sB = (u16*)(smem + 32768);    // 2 planes x [128][32] bf16 (2 x 8192 B)
  float* sC = (float*)smem;          // [4 waves][16 rows][100] epilogue (25600 B, reuse)

  const int tid  = threadIdx.x;
  const int lane = tid & 63;
  const int w    = tid >> 6;
  const int id   = blockIdx.x;
  const int work = ((id & 7) << 9) | (id >> 3);   // bijective, 4096 = 8*512
  const int m0   = (work & 3) << 8;               // 0,256,512,768
  const int nt   = work >> 2;                     // 0..1023
  const long n0  = (long)nt * 96;

  const int rA = lane >> 2, cA = (lane & 3) << 3;
  const int fr = lane & 15, fq = lane >> 4;

  const f32x4 z4 = {0.f, 0.f, 0.f, 0.f};
  f32x4 acc[4][6];
  #pragma unroll
  for (int i=0;i<4;i++)
    #pragma unroll
    for (int j=0;j<6;j++) acc[i][j] = z4;

  auto stage = [&](int s){                        // K-step s: k = s*64 .. s*64+63
    #pragma unroll
    for (int h = 0; h < 2; ++h){
      const int kofs = (s << 6) + (h << 5) + cA;
      u16* pA = sA + h*8192;                      // plane h (u16 units)
      u16* pB = sB + h*4096;
      #pragma unroll
      for (int cc = 0; cc < 4; ++cc){
        const int c = (w << 2) + cc;                       // 16 A chunks of 16 rows
        async16(pA + c*512, hmat + (long)(m0 + c*16 + rA)*512 + kofs);
      }
      #pragma unroll
      for (int cc = 0; cc < 2; ++cc){
        const int ch = (w << 1) + cc;                      // 8 B chunks (2 pad)
        int row = ch*16 + rA; if (row > 95) row = 95;      // clamp into valid rows
        async16(pB + ch*512, w2t + (n0 + row)*512 + kofs);
      }
    }
  };

  stage(0);
  for (int s = 0; s < 8; ++s){
    asm volatile("s_waitcnt vmcnt(0)" ::: "memory");       // own DMA(s) done
    __builtin_amdgcn_s_barrier();                          // -> all waves' DMA done
    bf16x8 af[2][4], bfv[2][6];
    #pragma unroll
    for (int h=0; h<2; ++h){
      #pragma unroll
      for (int i=0;i<4;i++)
        af[h][i] = *(const bf16x8*)(sA + h*8192 + ((w<<6) + i*16 + fr)*32 + (fq<<3));
      #pragma unroll
      for (int j=0;j<6;j++)
        bfv[h][j] = *(const bf16x8*)(sB + h*4096 + (j*16 + fr)*32 + (fq<<3));
    }
    asm volatile("s_waitcnt lgkmcnt(0)" ::: "memory");     // own ds_reads landed
    __builtin_amdgcn_sched_barrier(0);                     // rule #18 fence
    __builtin_amdgcn_s_barrier();                          // -> LDS reusable
    if (s < 7) stage(s + 1);                               // 12 DMA fly under MFMA
    __builtin_amdgcn_sched_barrier(0);                     // keep issue before MFMA
    #pragma unroll
    for (int h=0; h<2; ++h)
      #pragma unroll
      for (int i=0;i<4;i++)
        #pragma unroll
        for (int j=0;j<6;j++)
          acc[i][j] = __builtin_amdgcn_mfma_f32_16x16x32_bf16(af[h][i], bfv[h][j], acc[i][j], 0, 0, 0);
  }
  // barrier #2 of s=7 guarantees every wave's LDS reads are done -> sC reuse safe

  // ---- epilogue: RAW acc+b2 -> LDS -> per-(b,s_out) spline ----
  // myC regions are wave-private: no barriers needed inside (same-wave DS ops
  // are processed in order by the DS pipe; harness-verified across 9 rounds).
  // Three-pass register-diet spline (r9); phi staged in cols 96..99 ->
  // float4 coalesced stores; log-density via device atomics.
  const float shift = phase[0];
  float b2c[6];
  #pragma unroll
  for (int j=0;j<6;j++) b2c[j] = b2[n0 + j*16 + fr];
  float* myC = sC + w*1600;                                // 16 rows x 100 floats

  #pragma unroll
  for (int q = 0; q < 4; ++q){                             // quarter = row-frag index
    #pragma unroll
    for (int j=0;j<6;j++)
      #pragma unroll
      for (int r=0;r<4;r++)
        myC[((fq<<2)+r)*100 + j*16 + fr] = acc[q][j][r] + b2c[j];

    const int row = fr;                 // 0..15 within quarter
    const int g   = fq;                 // s_out group 0..3
    const float* tp = myC + row*100 + g*24;

    const int bg = m0 + (w<<6) + (q<<4) + row;
    const int s  = (nt<<2) + g;
    const float x = x_in[(long)bg*4096 + s];

    // pass 1: w_raw = tp[8..15]; sw (no array kept)
    const f32x4 w0 = *(const f32x4*)(tp + 8);
    const f32x4 w1 = *(const f32x4*)(tp + 12);
    float sw = 0.f;
    #pragma unroll
    for (int i=0;i<4;i++){ sw += exp_tanh(w0[i]); sw += exp_tanh(w1[i]); }

    // bin search in RAW cumsum space: cum_norm < x  <=>  cum_raw < x*sw/2pi
    const float xs = x * sw * (1.f / TWOPI_F);

    // pass 2: recompute ew, capture k / wkr / xkr by monotone overwrite
    float cw = 0.f, wkr = 0.f, xkr = 0.f; int k = 0;
    #pragma unroll
    for (int i=0;i<8;i++){
      const float e = exp_tanh(i < 4 ? w0[i] : w1[i-4]);
      if (cw < xs || i == 0){ k = i; wkr = e; xkr = cw; }
      cw += e;
    }

    // pass 3: h_raw = tp[0..7]; capture hkr / phr at i==k
    const f32x4 h0 = *(const f32x4*)(tp);
    const f32x4 h1 = *(const f32x4*)(tp + 4);
    float h2 = 0.f, hkr = 0.f, phr = 0.f;
    #pragma unroll
    for (int i=0;i<8;i++){
      const float e = exp_tanh(i < 4 ? h0[i] : h1[i-4]);
      if (i == k){ hkr = e; phr = h2; }
      h2 += e;
    }
    const float sh = h2;

    // only the 2 selected d values get tanh+softplus (runtime-indexed LDS read)
    const float* dp = tp + 16;
    const float th0 = tanh_nc(dp[k]);
    const float th1 = tanh_nc(dp[(k + 1) & 7]);
    const float dk  = __logf(1.f + __expf(th0));   // softplus, arg in (-1,1)
    const float dk1 = __logf(1.f + __expf(th1));

    const float rsh = rcpf(sh);
    const float rwk = rcpf(wkr);
    const float alpha = (xs - xkr) * rwk;          // == (x - x_{k-1})/w_k
    const float sk = hkr * rwk * (sw * rsh);       // == h_k/w_k
    const float hk = TWOPI_F * hkr * rsh;
    const float ph = TWOPI_F * phr * rsh;
    const float a1m = alpha * (1.f - alpha);
    const float denom = sk + (dk1 + dk - 2.f*sk)*a1m;
    const float rd = rcpf(denom);
    const float phiv = ph + hk*(sk*alpha*alpha + dk*a1m)*rd;
    float p = phiv + shift;                 // conditional subtract == mod
    if (p >= TWOPI_F) p -= TWOPI_F;
    if (p >= TWOPI_F) p -= TWOPI_F;
    myC[row*100 + 96 + g] = p;              // stage phi (cols 96..99 free)

    const float om = 1.f - alpha;
    const float num = dk1*alpha*alpha + 2.f*sk*a1m + dk*om*om;
    const float srd = sk * rd;
    float lg = __logf(srd*srd*num);         // == log(sk^2*num/denom^2)
    lg += __shfl_xor(lg, 16);               // sum over the 4 s_out groups (same row)
    lg += __shfl_xor(lg, 32);
    if (lane < 16){
      atomicAdd(ld + bg, -lg);              // device-scope, fire-and-forget
      const f32x4 pv = *(const f32x4*)(myC + lane*100 + 96);   // row = lane (==fr)
      const int bgr = m0 + (w<<6) + (q<<4) + lane;
      float4 o; o.x = pv[0]; o.y = pv[1]; o.z = pv[2]; o.w = pv[3];
      *(float4*)&phi_out[(long)bgr*4096 + (nt<<2)] = o;        // 16B coalesced
    }
  }
}

extern "C" void kernel_launch(void* const* d_in, const int* in_sizes, int n_in,
                              void* d_out, int out_size, void* d_ws, size_t ws_size,
                              hipStream_t stream){
  (void)in_sizes; (void)n_in; (void)out_size; (void)ws_size;
  const float* x_in  = (const float*)d_in[0];
  const float* x_pas = (const float*)d_in[1];
  const float* ldin  = (const float*)d_in[2];
  const float* w1    = (const float*)d_in[3];
  const float* b1    = (const float*)d_in[4];
  const float* w2    = (const float*)d_in[5];
  const float* b2    = (const float*)d_in[6];
  const float* phase = (const float*)d_in[7];
  float* out   = (float*)d_out;
  float* phi   = out;
  float* ldout = out + (size_t)1024*4096;

  // workspace layout (needs ~118.5 MB)
  char* ws = (char*)d_ws;
  float* stats = (float*)ws;                       // 8 B
  u16* xn   = (u16*)(ws + 256);                    // 8 MB   [1024][4096] bf16
  u16* w1t  = (u16*)(ws + 8388864);                // 4 MB   [512][4096] bf16
  u16* hb   = (u16*)(ws + 12583168);               // 1 MB   [1024][512] bf16
  u16* w2t  = (u16*)(ws + 13631744);               // 96 MB  [98304][512] bf16
  float* part = (float*)(ws + 114295040);          // 4 MB   gemm1 split-K partials

  hipMemsetAsync(stats, 0, 8, stream);
  k_stats<<<1024, 256, 0, stream>>>(x_pas, stats, ldin, ldout);
  k_prep<<<2048, 256, 0, stream>>>(x_pas, stats, xn);
  k_transpose_cvt<<<dim3(16, 4),  256, 0, stream>>>(w1, w1t, 4096, 512);
  k_transpose_cvt<<<dim3(2, 768), 256, 0, stream>>>(w2, w2t, 512, 98304);
  k_gemm1<<<dim3(8, 16, 2), 256, 0, stream>>>(xn, w1t, part);
  k_gemm1b<<<512, 256, 0, stream>>>(part, b1, hb);
  k_gemm2<<<dim3(4096), 256, 0, stream>>>(hb, w2t, b2, x_in, phase, phi, ldout);
}

// Round 12
// 546.340 us; speedup vs baseline: 1.0255x; 1.0088x over previous
//
#include <hip/hip_runtime.h>
#include <cstdint>
#include <cstddef>

// ---------------------------------------------------------------------------
// CircularSplineLayer pipeline:
//  k_stats          global sum/sumsq of x_passive; also ldout = ldin (free)
//  k_prep           xn -> bf16 [1024][4096]
//  k_transpose_cvt  f32 [K][N] -> bf16 [N][K], 256x128 tiles, XOR-swizzled LDS
//  k_gemm1          split-K=2 MFMA bf16, 4-deep LDS ring + counted vmcnt
//  k_gemm1b         combine partials + bias + tanh -> h bf16 [1024][512]
//  k_gemm2          256x96 tile, 4 waves, A single-buffer + B TWO-SLOT RING
//                   (32768B LDS): B (HBM-latency side) gets 2 kt-passes of
//                   DMA flight via counted vmcnt(2); A (L2-resident hmat)
//                   stays single-buffered. Costs no registers and no
//                   occupancy (LDS 32K -> 5 blocks by LDS, regs cap ~2.5).
//                   This is the one pipeline variant that pays for depth
//                   nowhere (r1/r3/r10/r11 each paid somewhere and lost).
//                   Atomic log-density; phi staged in LDS -> float4 stores.
// ---------------------------------------------------------------------------

typedef unsigned short u16;
typedef __bf16 bf16x8 __attribute__((ext_vector_type(8)));
typedef float f32x4 __attribute__((ext_vector_type(4)));
typedef unsigned short u16x8 __attribute__((ext_vector_type(8)));
typedef unsigned short u16x4 __attribute__((ext_vector_type(4)));
typedef unsigned short u16x2 __attribute__((ext_vector_type(2)));

#define TWOPI_F 6.28318530717958647692f

static __device__ __forceinline__ u16 f32_to_bf16(float f){
  unsigned u = __builtin_bit_cast(unsigned, f);
  return (u16)((u + 0x7fffu + ((u >> 16) & 1u)) >> 16);   // RNE
}
static __device__ __forceinline__ void async16(void* lds, const void* g){
  // global->LDS DMA, 16B/lane; LDS dest = wave-uniform base + lane*16
  __builtin_amdgcn_global_load_lds((const __attribute__((address_space(1))) void*)g,
                                   (__attribute__((address_space(3))) void*)lds,
                                   16, 0, 0);
}
static __device__ __forceinline__ float rcpf(float x){ return __builtin_amdgcn_rcpf(x); }
static __device__ __forceinline__ float fast_tanh(float x){
  x = fminf(fmaxf(x, -15.f), 15.f);
  float e = __expf(2.f * x);
  return (e - 1.f) / (e + 1.f);
}
// clamp-free tanh: 1 - 2/(e^{2x}+1); inf-safe (rcp(inf)=0 -> 1, rcp(1)=1 -> -1)
static __device__ __forceinline__ float tanh_nc(float x){
  const float e2 = __expf(2.f * x);
  return 1.f - 2.f * rcpf(e2 + 1.f);
}
// exp(tanh(x)) fused, clamp-free
static __device__ __forceinline__ float exp_tanh(float x){
  const float e2 = __expf(2.f * x);
  const float u  = rcpf(e2 + 1.f);
  return __expf(1.f - 2.f * u);
}

// ---- global sum / sumsq of x_passive (4194304 f32); ldout init piggyback ----
__global__ void k_stats(const float* __restrict__ xp, float* __restrict__ stats,
                        const float* __restrict__ ldin, float* __restrict__ ldout){
  __shared__ float ss[4], sq[4];
  const int tid = threadIdx.x;
  if (tid == 0) ldout[blockIdx.x] = ldin[blockIdx.x];    // 1024 blocks == B
  const long gt = (long)blockIdx.x * 256 + tid;          // float4 index
  const float4* x4 = (const float4*)xp;
  float s = 0.f, q = 0.f;
  #pragma unroll
  for (int p = 0; p < 4; ++p){
    float4 v = x4[gt + (long)p * 262144];
    s += v.x + v.y + v.z + v.w;
    q += v.x*v.x + v.y*v.y + v.z*v.z + v.w*v.w;
  }
  #pragma unroll
  for (int off = 32; off; off >>= 1){
    s += __shfl_down(s, off);
    q += __shfl_down(q, off);
  }
  if ((tid & 63) == 0){ ss[tid>>6] = s; sq[tid>>6] = q; }
  __syncthreads();
  if (tid == 0){
    atomicAdd(stats,     ss[0]+ss[1]+ss[2]+ss[3]);
    atomicAdd(stats + 1, sq[0]+sq[1]+sq[2]+sq[3]);
  }
}

// ---- xn = (x - mean)*istd -> bf16 ----
__global__ void k_prep(const float* __restrict__ xp, const float* __restrict__ stats,
                       u16* __restrict__ xn){
  const long t = (long)blockIdx.x * 256 + threadIdx.x;   // 524288 threads, 8 elems each
  const float sum = stats[0], sq = stats[1];
  const float N = 4194304.f;
  const float mean = sum / N;
  const float istd = rsqrtf((sq - sum*sum/N) / (N - 1.f));  // ddof=1
  const float4* x4 = (const float4*)xp;
  const float4 a = x4[2*t], b = x4[2*t+1];
  u16x8 o;
  o[0]=f32_to_bf16((a.x-mean)*istd); o[1]=f32_to_bf16((a.y-mean)*istd);
  o[2]=f32_to_bf16((a.z-mean)*istd); o[3]=f32_to_bf16((a.w-mean)*istd);
  o[4]=f32_to_bf16((b.x-mean)*istd); o[5]=f32_to_bf16((b.y-mean)*istd);
  o[6]=f32_to_bf16((b.z-mean)*istd); o[7]=f32_to_bf16((b.w-mean)*istd);
  ((u16x8*)xn)[t] = o;
}

// ---- f32 [Kd][Nd] -> bf16 [Nd][Kd]; 256(k) x 128(n) tiles ----
// Store: k-pair P of row n lands at pair-position P ^ (sigma<<2), sigma=(n>>2)&7
// (an XOR on the pair-GROUP index P>>2). Read: pair-group lk is therefore at
// group-position lk ^ sigma. Global reads AND writes stay 512B-contiguous.
__global__ __launch_bounds__(256) void k_transpose_cvt(const float* __restrict__ in,
                                                       u16* __restrict__ out,
                                                       int Kd, int Nd){
  __shared__ __align__(16) u16 tT[128*256];
  const int tid = threadIdx.x;
  const long k0 = (long)blockIdx.x * 256, n0 = (long)blockIdx.y * 128;
  const int lam = tid & 31, g = tid >> 5;
  const int c = lam * 4;
  const int sig = (lam & 7) << 2;                 // (sigma)<<2, sigma=(n>>2)&7
  #pragma unroll
  for (int pass = 0; pass < 16; ++pass){
    const int P = pass*8 + g;                     // k-pair index 0..127
    const float4 f0 = *(const float4*)&in[(k0 + 2*P    )*Nd + n0 + c];
    const float4 f1 = *(const float4*)&in[(k0 + 2*P + 1)*Nd + n0 + c];
    const int pp = 2*(P ^ sig);
    *(u16x2*)&tT[(c    )*256 + pp] = u16x2{f32_to_bf16(f0.x), f32_to_bf16(f1.x)};
    *(u16x2*)&tT[(c + 1)*256 + pp] = u16x2{f32_to_bf16(f0.y), f32_to_bf16(f1.y)};
    *(u16x2*)&tT[(c + 2)*256 + pp] = u16x2{f32_to_bf16(f0.z), f32_to_bf16(f1.z)};
    *(u16x2*)&tT[(c + 3)*256 + pp] = u16x2{f32_to_bf16(f0.w), f32_to_bf16(f1.w)};
  }
  __syncthreads();
  const int w = tid >> 6, l = tid & 63;
  const int lh = l >> 5, lk = l & 31;
  #pragma unroll
  for (int it = 0; it < 16; ++it){
    const int n = (w << 5) + (it << 1) + lh;
    const int s2 = (n >> 2) & 7;                  // sigma (group-index XOR) — NOT <<2
    const u16x8 v = *(const u16x8*)&tT[n*256 + 8*(lk ^ s2)];
    *(u16x8*)&out[(n0 + n)*Kd + k0 + 8*lk] = v;
  }
}

// ---- GEMM1 split-K: partial = xn @ w1 over half of K. M=1024 N=512 ----
// 4-deep LDS ring, prefetch depth 2, counted vmcnt (2 DMA instrs/wave/stage).
__global__ __launch_bounds__(256, 2) void k_gemm1(
    const u16* __restrict__ xn,   // [1024][4096] bf16
    const u16* __restrict__ w1t,  // [512][4096] bf16 (n-major)
    float* __restrict__ pp)       // [2][1024][512] f32 partials
{
  __shared__ __align__(16) u16 sA[4][64*32];
  __shared__ __align__(16) u16 sB[4][64*32];
  const int tid = threadIdx.x, lane = tid & 63, w = tid >> 6;
  const int n0 = blockIdx.x << 6, m0 = blockIdx.y << 6;
  const int ks = blockIdx.z;
  const int wm = w >> 1, wn = w & 1;
  const int rA = lane >> 2, cA = (lane & 3) << 3;
  const int fr = lane & 15, fq = lane >> 4;
  const f32x4 z4 = {0.f, 0.f, 0.f, 0.f};
  f32x4 acc[2][2];
  #pragma unroll
  for (int i=0;i<2;i++){ acc[i][0] = z4; acc[i][1] = z4; }

  auto stage = [&](int kt){
    const int b = kt & 3;
    const int kofs = (ks << 11) + (kt << 5) + cA;
    async16(sA[b] + w*512, xn  + (long)(m0 + w*16 + rA)*4096 + kofs);
    async16(sB[b] + w*512, w1t + (long)(n0 + w*16 + rA)*4096 + kofs);
  };

  stage(0); stage(1);
  for (int kt = 0; kt < 64; ++kt){
    if (kt < 62){
      stage(kt + 2);
      asm volatile("s_waitcnt vmcnt(4)" ::: "memory");   // kt's 2 DMAs done
    } else if (kt == 62){
      asm volatile("s_waitcnt vmcnt(2)" ::: "memory");
    } else {
      asm volatile("s_waitcnt vmcnt(0)" ::: "memory");
    }
    __builtin_amdgcn_s_barrier();
    const int b = kt & 3;
    bf16x8 af[2], bfv[2];
    #pragma unroll
    for (int i=0;i<2;i++) af[i]  = *(const bf16x8*)(sA[b] + ((wm<<5) + i*16 + fr)*32 + (fq<<3));
    #pragma unroll
    for (int j=0;j<2;j++) bfv[j] = *(const bf16x8*)(sB[b] + ((wn<<5) + j*16 + fr)*32 + (fq<<3));
    #pragma unroll
    for (int i=0;i<2;i++)
      #pragma unroll
      for (int j=0;j<2;j++)
        acc[i][j] = __builtin_amdgcn_mfma_f32_16x16x32_bf16(af[i], bfv[j], acc[i][j], 0, 0, 0);
  }
  float* po = pp + ((size_t)ks << 19);
  #pragma unroll
  for (int i=0;i<2;i++)
    #pragma unroll
    for (int j=0;j<2;j++)
      #pragma unroll
      for (int r=0;r<4;r++){
        const int row = m0 + (wm<<5) + i*16 + (fq<<2) + r;   // C/D: row=(lane>>4)*4+reg
        const int col = n0 + (wn<<5) + j*16 + fr;            //      col=lane&15
        po[row*512 + col] = acc[i][j][r];
      }
}

// ---- combine split-K partials: h = tanh(p0+p1+b1) -> bf16 ----
__global__ void k_gemm1b(const float* __restrict__ pp, const float* __restrict__ b1,
                         u16* __restrict__ hb){
  const int t = blockIdx.x * 256 + threadIdx.x;    // 131072 float4 groups
  const float4 a = ((const float4*)pp)[t];
  const float4 b = ((const float4*)pp)[131072 + t];
  const float4 bb = ((const float4*)b1)[t & 127];
  u16x4 o;
  o[0] = f32_to_bf16(fast_tanh(a.x + b.x + bb.x));
  o[1] = f32_to_bf16(fast_tanh(a.y + b.y + bb.y));
  o[2] = f32_to_bf16(fast_tanh(a.z + b.z + bb.z));
  o[3] = f32_to_bf16(fast_tanh(a.w + b.w + bb.w));
  ((u16x4*)hb)[t] = o;
}

// ---- GEMM2 + spline epilogue: M=1024 N=98304 K=512, tile 256x96 ----
// 1-D grid 4096, bijective XCD-chunked swizzle: work = ((id&7)<<9)|(id>>3).
// A single-buffer [256][32] + B 2-slot ring (2 x [128][32]); LDS 32768 B.
// Schedule per kt:
//   wait vmcnt(2)  [kt<15; kt=15 -> 0]  : A(kt),B(kt) done; B(kt+2)'s 2 DMAs
//                                         stay IN FLIGHT across the barrier
//   barrier / ds_read frags / lgkmcnt(0)+sched_barrier / barrier2
//   stageA(kt+1) x4, stageB(kt+2) x2    : issued in THIS order (ledger)
//   24 MFMA
// Ledger: at top of kt, outstanding = [.., A(kt)x4, B(kt+1)x2] from kt-1's
// group; vmcnt(2) completes A(kt) (and older B(kt)), leaves B(kt+1)... wait
// naming: group issued at iter j is {A(j+1), B(j+2)}. At top of kt the newest
// 2 instrs are B(kt+1) -- issued at kt-1 -- so vmcnt(2) completes A(kt)
// [issued kt-1] and B(kt) [issued kt-2, older]. B thus flies ~2 full passes
// (covers ~900cy HBM); A flies one MFMA block (covers L2).
// Slot safety: stageB(kt+2) writes slot (kt+2)&1 == kt&1 = B(kt)'s slot,
// whose reads were lgkm-drained by every wave before barrier2. Same proven
// argument covers stageA. Epilogue runs after kt=15's vmcnt(0): no DMA in
// flight touches LDS during sC reuse.
__global__ __launch_bounds__(256, 2) void k_gemm2(
    const u16* __restrict__ hmat,   // [1024][512] bf16
    const u16* __restrict__ w2t,    // [98304][512] bf16 (n-major)
    const float* __restrict__ b2,
    const float* __restrict__ x_in, // [1024][4096]
    const float* __restrict__ phase,
    float* __restrict__ phi_out,    // [1024][4096]
    float* __restrict__ ld)         // [1024] log-density accumulator (pre-init = ldin)
{
  __shared__ __align__(16) char smem[32768];
  u16* sA  = (u16*)smem;             // [256][32] bf16 (16384 B)
  u16* sB0 = (u16*)(smem + 16384);   // 2 slots x [128][32] bf16 (2 x 8192 B)
  float* sC = (float*)smem;          // [4 waves][16 rows][100] epilogue (25600 B, reuse)

  const int tid  = threadIdx.x;
  const int lane = tid & 63;
  const int w    = tid >> 6;
  const int id   = blockIdx.x;
  const int work = ((id & 7) << 9) | (id >> 3);   // bijective, 4096 = 8*512
  const int m0   = (work & 3) << 8;               // 0,256,512,768
  const int nt   = work >> 2;                     // 0..1023
  const long n0  = (long)nt * 96;

  const int rA = lane >> 2, cA = (lane & 3) << 3;
  const int fr = lane & 15, fq = lane >> 4;

  const f32x4 z4 = {0.f, 0.f, 0.f, 0.f};
  f32x4 acc[4][6];
  #pragma unroll
  for (int i=0;i<4;i++)
    #pragma unroll
    for (int j=0;j<6;j++) acc[i][j] = z4;

  auto stageA = [&](int kt){
    const int kofs = (kt << 5) + cA;
    #pragma unroll
    for (int cc = 0; cc < 4; ++cc){
      const int c = (w << 2) + cc;                         // 16 A chunks of 16 rows
      async16(sA + c*512, hmat + (long)(m0 + c*16 + rA)*512 + kofs);
    }
  };
  auto stageB = [&](int kt){
    u16* pB = sB0 + ((kt & 1) << 12);             // slot kt&1 (4096 u16)
    const int kofs = (kt << 5) + cA;
    #pragma unroll
    for (int cc = 0; cc < 2; ++cc){
      const int ch = (w << 1) + cc;                        // 8 B chunks (2 pad)
      int row = ch*16 + rA; if (row > 95) row = 95;        // clamp into valid rows
      async16(pB + ch*512, w2t + (n0 + row)*512 + kofs);
    }
  };

  stageA(0); stageB(0); stageB(1);                // prologue: A0,B0 waited at kt=0
  for (int kt = 0; kt < 16; ++kt){
    if (kt < 15) asm volatile("s_waitcnt vmcnt(2)" ::: "memory");  // A(kt),B(kt) done
    else         asm volatile("s_waitcnt vmcnt(0)" ::: "memory");
    __builtin_amdgcn_s_barrier();                          // -> all waves' data ready
    const u16* bB = sB0 + ((kt & 1) << 12);
    bf16x8 af[4], bfv[6];
    #pragma unroll
    for (int i=0;i<4;i++)
      af[i] = *(const bf16x8*)(sA + ((w<<6) + i*16 + fr)*32 + (fq<<3));
    #pragma unroll
    for (int j=0;j<6;j++)
      bfv[j] = *(const bf16x8*)(bB + (j*16 + fr)*32 + (fq<<3));
    asm volatile("s_waitcnt lgkmcnt(0)" ::: "memory");     // own ds_reads landed
    __builtin_amdgcn_sched_barrier(0);                     // rule #18 fence
    __builtin_amdgcn_s_barrier();                          // -> LDS slots reusable
    if (kt < 15) stageA(kt + 1);                           // issue order: A then B
    if (kt < 14) stageB(kt + 2);                           // (vmcnt ledger depends on it)
    __builtin_amdgcn_sched_barrier(0);                     // keep issue before MFMA
    #pragma unroll
    for (int i=0;i<4;i++)
      #pragma unroll
      for (int j=0;j<6;j++)
        acc[i][j] = __builtin_amdgcn_mfma_f32_16x16x32_bf16(af[i], bfv[j], acc[i][j], 0, 0, 0);
  }
  // kt=15 waited vmcnt(0) and issued nothing: no DMA in flight -> sC reuse safe

  // ---- epilogue: RAW acc+b2 -> LDS -> per-(b,s_out) spline ----
  // myC regions are wave-private: no barriers needed inside (same-wave DS ops
  // are processed in order by the DS pipe; harness-verified across 10 rounds).
  // Three-pass register-diet spline (r9); phi staged in cols 96..99 ->
  // float4 coalesced stores; log-density via device atomics.
  const float shift = phase[0];
  float b2c[6];
  #pragma unroll
  for (int j=0;j<6;j++) b2c[j] = b2[n0 + j*16 + fr];
  float* myC = sC + w*1600;                                // 16 rows x 100 floats

  #pragma unroll
  for (int q = 0; q < 4; ++q){                             // quarter = row-frag index
    #pragma unroll
    for (int j=0;j<6;j++)
      #pragma unroll
      for (int r=0;r<4;r++)
        myC[((fq<<2)+r)*100 + j*16 + fr] = acc[q][j][r] + b2c[j];

    const int row = fr;                 // 0..15 within quarter
    const int g   = fq;                 // s_out group 0..3
    const float* tp = myC + row*100 + g*24;

    const int bg = m0 + (w<<6) + (q<<4) + row;
    const int s  = (nt<<2) + g;
    const float x = x_in[(long)bg*4096 + s];

    // pass 1: w_raw = tp[8..15]; sw (no array kept)
    const f32x4 w0 = *(const f32x4*)(tp + 8);
    const f32x4 w1 = *(const f32x4*)(tp + 12);
    float sw = 0.f;
    #pragma unroll
    for (int i=0;i<4;i++){ sw += exp_tanh(w0[i]); sw += exp_tanh(w1[i]); }

    // bin search in RAW cumsum space: cum_norm < x  <=>  cum_raw < x*sw/2pi
    const float xs = x * sw * (1.f / TWOPI_F);

    // pass 2: recompute ew, capture k / wkr / xkr by monotone overwrite
    float cw = 0.f, wkr = 0.f, xkr = 0.f; int k = 0;
    #pragma unroll
    for (int i=0;i<8;i++){
      const float e = exp_tanh(i < 4 ? w0[i] : w1[i-4]);
      if (cw < xs || i == 0){ k = i; wkr = e; xkr = cw; }
      cw += e;
    }

    // pass 3: h_raw = tp[0..7]; capture hkr / phr at i==k
    const f32x4 h0 = *(const f32x4*)(tp);
    const f32x4 h1 = *(const f32x4*)(tp + 4);
    float h2 = 0.f, hkr = 0.f, phr = 0.f;
    #pragma unroll
    for (int i=0;i<8;i++){
      const float e = exp_tanh(i < 4 ? h0[i] : h1[i-4]);
      if (i == k){ hkr = e; phr = h2; }
      h2 += e;
    }
    const float sh = h2;

    // only the 2 selected d values get tanh+softplus (runtime-indexed LDS read)
    const float* dp = tp + 16;
    const float th0 = tanh_nc(dp[k]);
    const float th1 = tanh_nc(dp[(k + 1) & 7]);
    const float dk  = __logf(1.f + __expf(th0));   // softplus, arg in (-1,1)
    const float dk1 = __logf(1.f + __expf(th1));

    const float rsh = rcpf(sh);
    const float rwk = rcpf(wkr);
    const float alpha = (xs - xkr) * rwk;          // == (x - x_{k-1})/w_k
    const float sk = hkr * rwk * (sw * rsh);       // == h_k/w_k
    const float hk = TWOPI_F * hkr * rsh;
    const float ph = TWOPI_F * phr * rsh;
    const float a1m = alpha * (1.f - alpha);
    const float denom = sk + (dk1 + dk - 2.f*sk)*a1m;
    const float rd = rcpf(denom);
    const float phiv = ph + hk*(sk*alpha*alpha + dk*a1m)*rd;
    float p = phiv + shift;                 // conditional subtract == mod
    if (p >= TWOPI_F) p -= TWOPI_F;
    if (p >= TWOPI_F) p -= TWOPI_F;
    myC[row*100 + 96 + g] = p;              // stage phi (cols 96..99 free)

    const float om = 1.f - alpha;
    const float num = dk1*alpha*alpha + 2.f*sk*a1m + dk*om*om;
    const float srd = sk * rd;
    float lg = __logf(srd*srd*num);         // == log(sk^2*num/denom^2)
    lg += __shfl_xor(lg, 16);               // sum over the 4 s_out groups (same row)
    lg += __shfl_xor(lg, 32);
    if (lane < 16){
      atomicAdd(ld + bg, -lg);              // device-scope, fire-and-forget
      const f32x4 pv = *(const f32x4*)(myC + lane*100 + 96);   // row = lane (==fr)
      const int bgr = m0 + (w<<6) + (q<<4) + lane;
      float4 o; o.x = pv[0]; o.y = pv[1]; o.z = pv[2]; o.w = pv[3];
      *(float4*)&phi_out[(long)bgr*4096 + (nt<<2)] = o;        // 16B coalesced
    }
  }
}

extern "C" void kernel_launch(void* const* d_in, const int* in_sizes, int n_in,
                              void* d_out, int out_size, void* d_ws, size_t ws_size,
                              hipStream_t stream){
  (void)in_sizes; (void)n_in; (void)out_size; (void)ws_size;
  const float* x_in  = (const float*)d_in[0];
  const float* x_pas = (const float*)d_in[1];
  const float* ldin  = (const float*)d_in[2];
  const float* w1    = (const float*)d_in[3];
  const float* b1    = (const float*)d_in[4];
  const float* w2    = (const float*)d_in[5];
  const float* b2    = (const float*)d_in[6];
  const float* phase = (const float*)d_in[7];
  float* out   = (float*)d_out;
  float* phi   = out;
  float* ldout = out + (size_t)1024*4096;

  // workspace layout (needs ~118.5 MB)
  char* ws = (char*)d_ws;
  float* stats = (float*)ws;                       // 8 B
  u16* xn   = (u16*)(ws + 256);                    // 8 MB   [1024][4096] bf16
  u16* w1t  = (u16*)(ws + 8388864);                // 4 MB   [512][4096] bf16
  u16* hb   = (u16*)(ws + 12583168);               // 1 MB   [1024][512] bf16
  u16* w2t  = (u16*)(ws + 13631744);               // 96 MB  [98304][512] bf16
  float* part = (float*)(ws + 114295040);          // 4 MB   gemm1 split-K partials

  hipMemsetAsync(stats, 0, 8, stream);
  k_stats<<<1024, 256, 0, stream>>>(x_pas, stats, ldin, ldout);
  k_prep<<<2048, 256, 0, stream>>>(x_pas, stats, xn);
  k_transpose_cvt<<<dim3(16, 4),  256, 0, stream>>>(w1, w1t, 4096, 512);
  k_transpose_cvt<<<dim3(2, 768), 256, 0, stream>>>(w2, w2t, 512, 98304);
  k_gemm1<<<dim3(8, 16, 2), 256, 0, stream>>>(xn, w1t, part);
  k_gemm1b<<<512, 256, 0, stream>>>(part, b1, hb);
  k_gemm2<<<dim3(4096), 256, 0, stream>>>(hb, w2t, b2, x_in, phase, phi, ldout);
}

// Round 13
// 534.216 us; speedup vs baseline: 1.0488x; 1.0227x over previous
//
#include <hip/hip_runtime.h>
#include <cstdint>
#include <cstddef>

// ---------------------------------------------------------------------------
// CircularSplineLayer pipeline:
//  k_stats          global sum/sumsq of x_passive; also ldout = ldin (free)
//  k_prep           xn -> bf16 [1024][4096]
//  k_transpose_cvt  f32 [K][N] -> bf16 [N][K], 256x128 tiles, XOR-swizzled LDS
//  k_gemm1          split-K=2 MFMA bf16, 4-deep LDS ring + counted vmcnt
//  k_gemm1b         combine partials + bias + tanh -> h bf16 [1024][512]
//  k_gemm2          BEST-KNOWN (r9) + T5 setprio: 16x16x32 MFMA tile 256x96,
//                   single-buffer 25600B, T14 issue-early split, XCD-chunked
//                   swizzle. s_setprio(1) around the MFMA cluster: the 2
//                   co-resident blocks are unsynchronized -> arbiter favors
//                   the MFMA-phase block over the stage-phase block (the
//                   cross-block coverage this schedule relies on).
//                   Atomic log-density; phi staged in LDS -> float4 stores.
// ---------------------------------------------------------------------------

typedef unsigned short u16;
typedef __bf16 bf16x8 __attribute__((ext_vector_type(8)));
typedef float f32x4 __attribute__((ext_vector_type(4)));
typedef unsigned short u16x8 __attribute__((ext_vector_type(8)));
typedef unsigned short u16x4 __attribute__((ext_vector_type(4)));
typedef unsigned short u16x2 __attribute__((ext_vector_type(2)));

#define TWOPI_F 6.28318530717958647692f

static __device__ __forceinline__ u16 f32_to_bf16(float f){
  unsigned u = __builtin_bit_cast(unsigned, f);
  return (u16)((u + 0x7fffu + ((u >> 16) & 1u)) >> 16);   // RNE
}
static __device__ __forceinline__ void async16(void* lds, const void* g){
  // global->LDS DMA, 16B/lane; LDS dest = wave-uniform base + lane*16
  __builtin_amdgcn_global_load_lds((const __attribute__((address_space(1))) void*)g,
                                   (__attribute__((address_space(3))) void*)lds,
                                   16, 0, 0);
}
static __device__ __forceinline__ float rcpf(float x){ return __builtin_amdgcn_rcpf(x); }
static __device__ __forceinline__ float fast_tanh(float x){
  x = fminf(fmaxf(x, -15.f), 15.f);
  float e = __expf(2.f * x);
  return (e - 1.f) / (e + 1.f);
}
// clamp-free tanh: 1 - 2/(e^{2x}+1); inf-safe (rcp(inf)=0 -> 1, rcp(1)=1 -> -1)
static __device__ __forceinline__ float tanh_nc(float x){
  const float e2 = __expf(2.f * x);
  return 1.f - 2.f * rcpf(e2 + 1.f);
}
// exp(tanh(x)) fused, clamp-free
static __device__ __forceinline__ float exp_tanh(float x){
  const float e2 = __expf(2.f * x);
  const float u  = rcpf(e2 + 1.f);
  return __expf(1.f - 2.f * u);
}

// ---- global sum / sumsq of x_passive (4194304 f32); ldout init piggyback ----
__global__ void k_stats(const float* __restrict__ xp, float* __restrict__ stats,
                        const float* __restrict__ ldin, float* __restrict__ ldout){
  __shared__ float ss[4], sq[4];
  const int tid = threadIdx.x;
  if (tid == 0) ldout[blockIdx.x] = ldin[blockIdx.x];    // 1024 blocks == B
  const long gt = (long)blockIdx.x * 256 + tid;          // float4 index
  const float4* x4 = (const float4*)xp;
  float s = 0.f, q = 0.f;
  #pragma unroll
  for (int p = 0; p < 4; ++p){
    float4 v = x4[gt + (long)p * 262144];
    s += v.x + v.y + v.z + v.w;
    q += v.x*v.x + v.y*v.y + v.z*v.z + v.w*v.w;
  }
  #pragma unroll
  for (int off = 32; off; off >>= 1){
    s += __shfl_down(s, off);
    q += __shfl_down(q, off);
  }
  if ((tid & 63) == 0){ ss[tid>>6] = s; sq[tid>>6] = q; }
  __syncthreads();
  if (tid == 0){
    atomicAdd(stats,     ss[0]+ss[1]+ss[2]+ss[3]);
    atomicAdd(stats + 1, sq[0]+sq[1]+sq[2]+sq[3]);
  }
}

// ---- xn = (x - mean)*istd -> bf16 ----
__global__ void k_prep(const float* __restrict__ xp, const float* __restrict__ stats,
                       u16* __restrict__ xn){
  const long t = (long)blockIdx.x * 256 + threadIdx.x;   // 524288 threads, 8 elems each
  const float sum = stats[0], sq = stats[1];
  const float N = 4194304.f;
  const float mean = sum / N;
  const float istd = rsqrtf((sq - sum*sum/N) / (N - 1.f));  // ddof=1
  const float4* x4 = (const float4*)xp;
  const float4 a = x4[2*t], b = x4[2*t+1];
  u16x8 o;
  o[0]=f32_to_bf16((a.x-mean)*istd); o[1]=f32_to_bf16((a.y-mean)*istd);
  o[2]=f32_to_bf16((a.z-mean)*istd); o[3]=f32_to_bf16((a.w-mean)*istd);
  o[4]=f32_to_bf16((b.x-mean)*istd); o[5]=f32_to_bf16((b.y-mean)*istd);
  o[6]=f32_to_bf16((b.z-mean)*istd); o[7]=f32_to_bf16((b.w-mean)*istd);
  ((u16x8*)xn)[t] = o;
}

// ---- f32 [Kd][Nd] -> bf16 [Nd][Kd]; 256(k) x 128(n) tiles ----
// Store: k-pair P of row n lands at pair-position P ^ (sigma<<2), sigma=(n>>2)&7
// (an XOR on the pair-GROUP index P>>2). Read: pair-group lk is therefore at
// group-position lk ^ sigma. Global reads AND writes stay 512B-contiguous.
__global__ __launch_bounds__(256) void k_transpose_cvt(const float* __restrict__ in,
                                                       u16* __restrict__ out,
                                                       int Kd, int Nd){
  __shared__ __align__(16) u16 tT[128*256];
  const int tid = threadIdx.x;
  const long k0 = (long)blockIdx.x * 256, n0 = (long)blockIdx.y * 128;
  const int lam = tid & 31, g = tid >> 5;
  const int c = lam * 4;
  const int sig = (lam & 7) << 2;                 // (sigma)<<2, sigma=(n>>2)&7
  #pragma unroll
  for (int pass = 0; pass < 16; ++pass){
    const int P = pass*8 + g;                     // k-pair index 0..127
    const float4 f0 = *(const float4*)&in[(k0 + 2*P    )*Nd + n0 + c];
    const float4 f1 = *(const float4*)&in[(k0 + 2*P + 1)*Nd + n0 + c];
    const int pp = 2*(P ^ sig);
    *(u16x2*)&tT[(c    )*256 + pp] = u16x2{f32_to_bf16(f0.x), f32_to_bf16(f1.x)};
    *(u16x2*)&tT[(c + 1)*256 + pp] = u16x2{f32_to_bf16(f0.y), f32_to_bf16(f1.y)};
    *(u16x2*)&tT[(c + 2)*256 + pp] = u16x2{f32_to_bf16(f0.z), f32_to_bf16(f1.z)};
    *(u16x2*)&tT[(c + 3)*256 + pp] = u16x2{f32_to_bf16(f0.w), f32_to_bf16(f1.w)};
  }
  __syncthreads();
  const int w = tid >> 6, l = tid & 63;
  const int lh = l >> 5, lk = l & 31;
  #pragma unroll
  for (int it = 0; it < 16; ++it){
    const int n = (w << 5) + (it << 1) + lh;
    const int s2 = (n >> 2) & 7;                  // sigma (group-index XOR) — NOT <<2
    const u16x8 v = *(const u16x8*)&tT[n*256 + 8*(lk ^ s2)];
    *(u16x8*)&out[(n0 + n)*Kd + k0 + 8*lk] = v;
  }
}

// ---- GEMM1 split-K: partial = xn @ w1 over half of K. M=1024 N=512 ----
// 4-deep LDS ring, prefetch depth 2, counted vmcnt (2 DMA instrs/wave/stage).
__global__ __launch_bounds__(256, 2) void k_gemm1(
    const u16* __restrict__ xn,   // [1024][4096] bf16
    const u16* __restrict__ w1t,  // [512][4096] bf16 (n-major)
    float* __restrict__ pp)       // [2][1024][512] f32 partials
{
  __shared__ __align__(16) u16 sA[4][64*32];
  __shared__ __align__(16) u16 sB[4][64*32];
  const int tid = threadIdx.x, lane = tid & 63, w = tid >> 6;
  const int n0 = blockIdx.x << 6, m0 = blockIdx.y << 6;
  const int ks = blockIdx.z;
  const int wm = w >> 1, wn = w & 1;
  const int rA = lane >> 2, cA = (lane & 3) << 3;
  const int fr = lane & 15, fq = lane >> 4;
  const f32x4 z4 = {0.f, 0.f, 0.f, 0.f};
  f32x4 acc[2][2];
  #pragma unroll
  for (int i=0;i<2;i++){ acc[i][0] = z4; acc[i][1] = z4; }

  auto stage = [&](int kt){
    const int b = kt & 3;
    const int kofs = (ks << 11) + (kt << 5) + cA;
    async16(sA[b] + w*512, xn  + (long)(m0 + w*16 + rA)*4096 + kofs);
    async16(sB[b] + w*512, w1t + (long)(n0 + w*16 + rA)*4096 + kofs);
  };

  stage(0); stage(1);
  for (int kt = 0; kt < 64; ++kt){
    if (kt < 62){
      stage(kt + 2);
      asm volatile("s_waitcnt vmcnt(4)" ::: "memory");   // kt's 2 DMAs done
    } else if (kt == 62){
      asm volatile("s_waitcnt vmcnt(2)" ::: "memory");
    } else {
      asm volatile("s_waitcnt vmcnt(0)" ::: "memory");
    }
    __builtin_amdgcn_s_barrier();
    const int b = kt & 3;
    bf16x8 af[2], bfv[2];
    #pragma unroll
    for (int i=0;i<2;i++) af[i]  = *(const bf16x8*)(sA[b] + ((wm<<5) + i*16 + fr)*32 + (fq<<3));
    #pragma unroll
    for (int j=0;j<2;j++) bfv[j] = *(const bf16x8*)(sB[b] + ((wn<<5) + j*16 + fr)*32 + (fq<<3));
    #pragma unroll
    for (int i=0;i<2;i++)
      #pragma unroll
      for (int j=0;j<2;j++)
        acc[i][j] = __builtin_amdgcn_mfma_f32_16x16x32_bf16(af[i], bfv[j], acc[i][j], 0, 0, 0);
  }
  float* po = pp + ((size_t)ks << 19);
  #pragma unroll
  for (int i=0;i<2;i++)
    #pragma unroll
    for (int j=0;j<2;j++)
      #pragma unroll
      for (int r=0;r<4;r++){
        const int row = m0 + (wm<<5) + i*16 + (fq<<2) + r;   // C/D: row=(lane>>4)*4+reg
        const int col = n0 + (wn<<5) + j*16 + fr;            //      col=lane&15
        po[row*512 + col] = acc[i][j][r];
      }
}

// ---- combine split-K partials: h = tanh(p0+p1+b1) -> bf16 ----
__global__ void k_gemm1b(const float* __restrict__ pp, const float* __restrict__ b1,
                         u16* __restrict__ hb){
  const int t = blockIdx.x * 256 + threadIdx.x;    // 131072 float4 groups
  const float4 a = ((const float4*)pp)[t];
  const float4 b = ((const float4*)pp)[131072 + t];
  const float4 bb = ((const float4*)b1)[t & 127];
  u16x4 o;
  o[0] = f32_to_bf16(fast_tanh(a.x + b.x + bb.x));
  o[1] = f32_to_bf16(fast_tanh(a.y + b.y + bb.y));
  o[2] = f32_to_bf16(fast_tanh(a.z + b.z + bb.z));
  o[3] = f32_to_bf16(fast_tanh(a.w + b.w + bb.w));
  ((u16x4*)hb)[t] = o;
}

// ---- GEMM2 + spline epilogue: M=1024 N=98304 K=512, tile 256x96 ----
// 1-D grid 4096, bijective XCD-chunked swizzle: work = ((id&7)<<9)|(id>>3).
// Each XCD owns 512 consecutive works (m fastest) -> w2t strips L2-hit across
// the 4 m-tiles, x_in 128B lines fetched once.
// T14 per-kt async split (single buffer), r6/r8/r9 verbatim:
//   vmcnt(0)+barrier / ds_read+lgkm+sched_barrier+barrier / stage(kt+1) /
//   setprio(1) 24xMFMA setprio(0)
// T5: the 2 co-resident blocks are unsynchronized; setprio biases the SIMD
// arbiter toward the MFMA-phase block while the other block stages/drains.
__global__ __launch_bounds__(256, 2) void k_gemm2(
    const u16* __restrict__ hmat,   // [1024][512] bf16
    const u16* __restrict__ w2t,    // [98304][512] bf16 (n-major)
    const float* __restrict__ b2,
    const float* __restrict__ x_in, // [1024][4096]
    const float* __restrict__ phase,
    float* __restrict__ phi_out,    // [1024][4096]
    float* __restrict__ ld)         // [1024] log-density accumulator (pre-init = ldin)
{
  __shared__ __align__(16) char smem[25600];
  u16* sA = (u16*)smem;              // [256][32] bf16 staging
  u16* sB = (u16*)(smem + 16384);    // [128][32] bf16 (rows >=96 are pad)
  float* sC = (float*)smem;          // [4 waves][16 rows][100] epilogue (reuses smem)

  const int tid  = threadIdx.x;
  const int lane = tid & 63;
  const int w    = tid >> 6;
  const int id   = blockIdx.x;
  const int work = ((id & 7) << 9) | (id >> 3);   // bijective, 4096 = 8*512
  const int m0   = (work & 3) << 8;               // 0,256,512,768
  const int nt   = work >> 2;                     // 0..1023
  const long n0  = (long)nt * 96;

  const int rA = lane >> 2, cA = (lane & 3) << 3;
  const int fr = lane & 15, fq = lane >> 4;

  const f32x4 z4 = {0.f, 0.f, 0.f, 0.f};
  f32x4 acc[4][6];
  #pragma unroll
  for (int i=0;i<4;i++)
    #pragma unroll
    for (int j=0;j<6;j++) acc[i][j] = z4;

  auto stage = [&](int kt){
    const int kofs = (kt << 5) + cA;
    #pragma unroll
    for (int cc = 0; cc < 4; ++cc){
      const int c = (w << 2) + cc;                         // 16 A chunks of 16 rows
      async16(sA + c*512, hmat + (long)(m0 + c*16 + rA)*512 + kofs);
    }
    #pragma unroll
    for (int cc = 0; cc < 2; ++cc){
      const int ch = (w << 1) + cc;                        // 8 B chunks (2 pad)
      int row = ch*16 + rA; if (row > 95) row = 95;        // clamp into valid rows
      async16(sB + ch*512, w2t + (n0 + row)*512 + kofs);
    }
  };

  stage(0);
  for (int kt = 0; kt < 16; ++kt){
    asm volatile("s_waitcnt vmcnt(0)" ::: "memory");       // own DMA(kt) done
    __builtin_amdgcn_s_barrier();                          // -> all waves' DMA done
    bf16x8 af[4], bfv[6];
    #pragma unroll
    for (int i=0;i<4;i++)
      af[i] = *(const bf16x8*)(sA + ((w<<6) + i*16 + fr)*32 + (fq<<3));
    #pragma unroll
    for (int j=0;j<6;j++)
      bfv[j] = *(const bf16x8*)(sB + (j*16 + fr)*32 + (fq<<3));
    asm volatile("s_waitcnt lgkmcnt(0)" ::: "memory");     // own ds_reads landed
    __builtin_amdgcn_sched_barrier(0);                     // rule #18 fence
    __builtin_amdgcn_s_barrier();                          // -> LDS reusable
    if (kt < 15) stage(kt + 1);                            // DMA flies under MFMA
    __builtin_amdgcn_sched_barrier(0);                     // keep issue before MFMA
    __builtin_amdgcn_s_setprio(1);                         // T5: favor MFMA-phase block
    #pragma unroll
    for (int i=0;i<4;i++)
      #pragma unroll
      for (int j=0;j<6;j++)
        acc[i][j] = __builtin_amdgcn_mfma_f32_16x16x32_bf16(af[i], bfv[j], acc[i][j], 0, 0, 0);
    __builtin_amdgcn_s_setprio(0);
  }
  // barrier #2 of kt=15 guarantees every wave's LDS reads are done -> sC reuse safe

  // ---- epilogue: RAW acc+b2 -> LDS -> per-(b,s_out) spline ----
  // myC regions are wave-private: no barriers needed inside (same-wave DS ops
  // are processed in order by the DS pipe; harness-verified across 11 rounds).
  // Three-pass register-diet spline (r9); phi staged in cols 96..99 ->
  // float4 coalesced stores; log-density via device atomics.
  const float shift = phase[0];
  float b2c[6];
  #pragma unroll
  for (int j=0;j<6;j++) b2c[j] = b2[n0 + j*16 + fr];
  float* myC = sC + w*1600;                                // 16 rows x 100 floats

  #pragma unroll
  for (int q = 0; q < 4; ++q){                             // quarter = row-frag index
    #pragma unroll
    for (int j=0;j<6;j++)
      #pragma unroll
      for (int r=0;r<4;r++)
        myC[((fq<<2)+r)*100 + j*16 + fr] = acc[q][j][r] + b2c[j];

    const int row = fr;                 // 0..15 within quarter
    const int g   = fq;                 // s_out group 0..3
    const float* tp = myC + row*100 + g*24;

    const int bg = m0 + (w<<6) + (q<<4) + row;
    const int s  = (nt<<2) + g;
    const float x = x_in[(long)bg*4096 + s];

    // pass 1: w_raw = tp[8..15]; sw (no array kept)
    const f32x4 w0 = *(const f32x4*)(tp + 8);
    const f32x4 w1 = *(const f32x4*)(tp + 12);
    float sw = 0.f;
    #pragma unroll
    for (int i=0;i<4;i++){ sw += exp_tanh(w0[i]); sw += exp_tanh(w1[i]); }

    // bin search in RAW cumsum space: cum_norm < x  <=>  cum_raw < x*sw/2pi
    const float xs = x * sw * (1.f / TWOPI_F);

    // pass 2: recompute ew, capture k / wkr / xkr by monotone overwrite
    float cw = 0.f, wkr = 0.f, xkr = 0.f; int k = 0;
    #pragma unroll
    for (int i=0;i<8;i++){
      const float e = exp_tanh(i < 4 ? w0[i] : w1[i-4]);
      if (cw < xs || i == 0){ k = i; wkr = e; xkr = cw; }
      cw += e;
    }

    // pass 3: h_raw = tp[0..7]; capture hkr / phr at i==k
    const f32x4 h0 = *(const f32x4*)(tp);
    const f32x4 h1 = *(const f32x4*)(tp + 4);
    float h2 = 0.f, hkr = 0.f, phr = 0.f;
    #pragma unroll
    for (int i=0;i<8;i++){
      const float e = exp_tanh(i < 4 ? h0[i] : h1[i-4]);
      if (i == k){ hkr = e; phr = h2; }
      h2 += e;
    }
    const float sh = h2;

    // only the 2 selected d values get tanh+softplus (runtime-indexed LDS read)
    const float* dp = tp + 16;
    const float th0 = tanh_nc(dp[k]);
    const float th1 = tanh_nc(dp[(k + 1) & 7]);
    const float dk  = __logf(1.f + __expf(th0));   // softplus, arg in (-1,1)
    const float dk1 = __logf(1.f + __expf(th1));

    const float rsh = rcpf(sh);
    const float rwk = rcpf(wkr);
    const float alpha = (xs - xkr) * rwk;          // == (x - x_{k-1})/w_k
    const float sk = hkr * rwk * (sw * rsh);       // == h_k/w_k
    const float hk = TWOPI_F * hkr * rsh;
    const float ph = TWOPI_F * phr * rsh;
    const float a1m = alpha * (1.f - alpha);
    const float denom = sk + (dk1 + dk - 2.f*sk)*a1m;
    const float rd = rcpf(denom);
    const float phiv = ph + hk*(sk*alpha*alpha + dk*a1m)*rd;
    float p = phiv + shift;                 // conditional subtract == mod
    if (p >= TWOPI_F) p -= TWOPI_F;
    if (p >= TWOPI_F) p -= TWOPI_F;
    myC[row*100 + 96 + g] = p;              // stage phi (cols 96..99 free)

    const float om = 1.f - alpha;
    const float num = dk1*alpha*alpha + 2.f*sk*a1m + dk*om*om;
    const float srd = sk * rd;
    float lg = __logf(srd*srd*num);         // == log(sk^2*num/denom^2)
    lg += __shfl_xor(lg, 16);               // sum over the 4 s_out groups (same row)
    lg += __shfl_xor(lg, 32);
    if (lane < 16){
      atomicAdd(ld + bg, -lg);              // device-scope, fire-and-forget
      const f32x4 pv = *(const f32x4*)(myC + lane*100 + 96);   // row = lane (==fr)
      const int bgr = m0 + (w<<6) + (q<<4) + lane;
      float4 o; o.x = pv[0]; o.y = pv[1]; o.z = pv[2]; o.w = pv[3];
      *(float4*)&phi_out[(long)bgr*4096 + (nt<<2)] = o;        // 16B coalesced
    }
  }
}

extern "C" void kernel_launch(void* const* d_in, const int* in_sizes, int n_in,
                              void* d_out, int out_size, void* d_ws, size_t ws_size,
                              hipStream_t stream){
  (void)in_sizes; (void)n_in; (void)out_size; (void)ws_size;
  const float* x_in  = (const float*)d_in[0];
  const float* x_pas = (const float*)d_in[1];
  const float* ldin  = (const float*)d_in[2];
  const float* w1    = (const float*)d_in[3];
  const float* b1    = (const float*)d_in[4];
  const float* w2    = (const float*)d_in[5];
  const float* b2    = (const float*)d_in[6];
  const float* phase = (const float*)d_in[7];
  float* out   = (float*)d_out;
  float* phi   = out;
  float* ldout = out + (size_t)1024*4096;

  // workspace layout (needs ~118.5 MB)
  char* ws = (char*)d_ws;
  float* stats = (float*)ws;                       // 8 B
  u16* xn   = (u16*)(ws + 256);                    // 8 MB   [1024][4096] bf16
  u16* w1t  = (u16*)(ws + 8388864);                // 4 MB   [512][4096] bf16
  u16* hb   = (u16*)(ws + 12583168);               // 1 MB   [1024][512] bf16
  u16* w2t  = (u16*)(ws + 13631744);               // 96 MB  [98304][512] bf16
  float* part = (float*)(ws + 114295040);          // 4 MB   gemm1 split-K partials

  hipMemsetAsync(stats, 0, 8, stream);
  k_stats<<<1024, 256, 0, stream>>>(x_pas, stats, ldin, ldout);
  k_prep<<<2048, 256, 0, stream>>>(x_pas, stats, xn);
  k_transpose_cvt<<<dim3(16, 4),  256, 0, stream>>>(w1, w1t, 4096, 512);
  k_transpose_cvt<<<dim3(2, 768), 256, 0, stream>>>(w2, w2t, 512, 98304);
  k_gemm1<<<dim3(8, 16, 2), 256, 0, stream>>>(xn, w1t, part);
  k_gemm1b<<<512, 256, 0, stream>>>(part, b1, hb);
  k_gemm2<<<dim3(4096), 256, 0, stream>>>(hb, w2t, b2, x_in, phase, phi, ldout);
}

// Round 14
// 530.094 us; speedup vs baseline: 1.0570x; 1.0078x over previous
//
#include <hip/hip_runtime.h>
#include <cstdint>
#include <cstddef>

// ---------------------------------------------------------------------------
// CircularSplineLayer pipeline:
//  k_stats          global sum/sumsq of x_passive; also ldout = ldin (free)
//  k_prep           xn -> bf16 [1024][4096]
//  k_transpose_cvt  f32 [K][N] -> bf16 [N][K], 256x128 tiles, XOR-swizzled LDS
//  k_gemm1          split-K=2 MFMA bf16, 4-deep LDS ring, TRUE depth-3
//                   prefetch (r5 ledger: vmcnt(4), stage(kt+3) post-barrier)
//  k_gemm1b         combine partials + bias + tanh -> h bf16 [1024][512]
//  k_gemm2          r9 structure + B DOUBLE-BUFFER WITH EARLY ISSUE: stageB
//                   for kt+1 issues at bar1 of kt (one phase earlier than any
//                   prior attempt) into the opposite 8KB slot; ALL waits stay
//                   vmcnt(0) (no counted ledger -> minimal register delta vs
//                   r12's +8). B gets ~400-550cy flight (covers L3/HBM); A
//                   (L2-hot hmat) keeps MFMA-block flight (~matches L2 lat).
//                   Guard: arch VGPR must stay <=88 (84->92 costs 15us, r12).
//                   Atomic log-density; phi staged in LDS -> float4 stores.
// ---------------------------------------------------------------------------

typedef unsigned short u16;
typedef __bf16 bf16x8 __attribute__((ext_vector_type(8)));
typedef float f32x4 __attribute__((ext_vector_type(4)));
typedef unsigned short u16x8 __attribute__((ext_vector_type(8)));
typedef unsigned short u16x4 __attribute__((ext_vector_type(4)));
typedef unsigned short u16x2 __attribute__((ext_vector_type(2)));

#define TWOPI_F 6.28318530717958647692f

static __device__ __forceinline__ u16 f32_to_bf16(float f){
  unsigned u = __builtin_bit_cast(unsigned, f);
  return (u16)((u + 0x7fffu + ((u >> 16) & 1u)) >> 16);   // RNE
}
static __device__ __forceinline__ void async16(void* lds, const void* g){
  // global->LDS DMA, 16B/lane; LDS dest = wave-uniform base + lane*16
  __builtin_amdgcn_global_load_lds((const __attribute__((address_space(1))) void*)g,
                                   (__attribute__((address_space(3))) void*)lds,
                                   16, 0, 0);
}
static __device__ __forceinline__ float rcpf(float x){ return __builtin_amdgcn_rcpf(x); }
static __device__ __forceinline__ float fast_tanh(float x){
  x = fminf(fmaxf(x, -15.f), 15.f);
  float e = __expf(2.f * x);
  return (e - 1.f) / (e + 1.f);
}
// clamp-free tanh: 1 - 2/(e^{2x}+1); inf-safe (rcp(inf)=0 -> 1, rcp(1)=1 -> -1)
static __device__ __forceinline__ float tanh_nc(float x){
  const float e2 = __expf(2.f * x);
  return 1.f - 2.f * rcpf(e2 + 1.f);
}
// exp(tanh(x)) fused, clamp-free
static __device__ __forceinline__ float exp_tanh(float x){
  const float e2 = __expf(2.f * x);
  const float u  = rcpf(e2 + 1.f);
  return __expf(1.f - 2.f * u);
}

// ---- global sum / sumsq of x_passive (4194304 f32); ldout init piggyback ----
__global__ void k_stats(const float* __restrict__ xp, float* __restrict__ stats,
                        const float* __restrict__ ldin, float* __restrict__ ldout){
  __shared__ float ss[4], sq[4];
  const int tid = threadIdx.x;
  if (tid == 0) ldout[blockIdx.x] = ldin[blockIdx.x];    // 1024 blocks == B
  const long gt = (long)blockIdx.x * 256 + tid;          // float4 index
  const float4* x4 = (const float4*)xp;
  float s = 0.f, q = 0.f;
  #pragma unroll
  for (int p = 0; p < 4; ++p){
    float4 v = x4[gt + (long)p * 262144];
    s += v.x + v.y + v.z + v.w;
    q += v.x*v.x + v.y*v.y + v.z*v.z + v.w*v.w;
  }
  #pragma unroll
  for (int off = 32; off; off >>= 1){
    s += __shfl_down(s, off);
    q += __shfl_down(q, off);
  }
  if ((tid & 63) == 0){ ss[tid>>6] = s; sq[tid>>6] = q; }
  __syncthreads();
  if (tid == 0){
    atomicAdd(stats,     ss[0]+ss[1]+ss[2]+ss[3]);
    atomicAdd(stats + 1, sq[0]+sq[1]+sq[2]+sq[3]);
  }
}

// ---- xn = (x - mean)*istd -> bf16 ----
__global__ void k_prep(const float* __restrict__ xp, const float* __restrict__ stats,
                       u16* __restrict__ xn){
  const long t = (long)blockIdx.x * 256 + threadIdx.x;   // 524288 threads, 8 elems each
  const float sum = stats[0], sq = stats[1];
  const float N = 4194304.f;
  const float mean = sum / N;
  const float istd = rsqrtf((sq - sum*sum/N) / (N - 1.f));  // ddof=1
  const float4* x4 = (const float4*)xp;
  const float4 a = x4[2*t], b = x4[2*t+1];
  u16x8 o;
  o[0]=f32_to_bf16((a.x-mean)*istd); o[1]=f32_to_bf16((a.y-mean)*istd);
  o[2]=f32_to_bf16((a.z-mean)*istd); o[3]=f32_to_bf16((a.w-mean)*istd);
  o[4]=f32_to_bf16((b.x-mean)*istd); o[5]=f32_to_bf16((b.y-mean)*istd);
  o[6]=f32_to_bf16((b.z-mean)*istd); o[7]=f32_to_bf16((b.w-mean)*istd);
  ((u16x8*)xn)[t] = o;
}

// ---- f32 [Kd][Nd] -> bf16 [Nd][Kd]; 256(k) x 128(n) tiles ----
// Store: k-pair P of row n lands at pair-position P ^ (sigma<<2), sigma=(n>>2)&7
// (an XOR on the pair-GROUP index P>>2). Read: pair-group lk is therefore at
// group-position lk ^ sigma. Global reads AND writes stay 512B-contiguous.
__global__ __launch_bounds__(256) void k_transpose_cvt(const float* __restrict__ in,
                                                       u16* __restrict__ out,
                                                       int Kd, int Nd){
  __shared__ __align__(16) u16 tT[128*256];
  const int tid = threadIdx.x;
  const long k0 = (long)blockIdx.x * 256, n0 = (long)blockIdx.y * 128;
  const int lam = tid & 31, g = tid >> 5;
  const int c = lam * 4;
  const int sig = (lam & 7) << 2;                 // (sigma)<<2, sigma=(n>>2)&7
  #pragma unroll
  for (int pass = 0; pass < 16; ++pass){
    const int P = pass*8 + g;                     // k-pair index 0..127
    const float4 f0 = *(const float4*)&in[(k0 + 2*P    )*Nd + n0 + c];
    const float4 f1 = *(const float4*)&in[(k0 + 2*P + 1)*Nd + n0 + c];
    const int pp = 2*(P ^ sig);
    *(u16x2*)&tT[(c    )*256 + pp] = u16x2{f32_to_bf16(f0.x), f32_to_bf16(f1.x)};
    *(u16x2*)&tT[(c + 1)*256 + pp] = u16x2{f32_to_bf16(f0.y), f32_to_bf16(f1.y)};
    *(u16x2*)&tT[(c + 2)*256 + pp] = u16x2{f32_to_bf16(f0.z), f32_to_bf16(f1.z)};
    *(u16x2*)&tT[(c + 3)*256 + pp] = u16x2{f32_to_bf16(f0.w), f32_to_bf16(f1.w)};
  }
  __syncthreads();
  const int w = tid >> 6, l = tid & 63;
  const int lh = l >> 5, lk = l & 31;
  #pragma unroll
  for (int it = 0; it < 16; ++it){
    const int n = (w << 5) + (it << 1) + lh;
    const int s2 = (n >> 2) & 7;                  // sigma (group-index XOR) — NOT <<2
    const u16x8 v = *(const u16x8*)&tT[n*256 + 8*(lk ^ s2)];
    *(u16x8*)&out[(n0 + n)*Kd + k0 + 8*lk] = v;
  }
}

// ---- GEMM1 split-K: partial = xn @ w1 over half of K. M=1024 N=512 ----
// 4-deep LDS ring, TRUE prefetch depth 3 (1 block/CU: ~900cy HBM latency
// needs ~3 iterations of flight). Ledger: at top of kt outstanding =
// s(kt),s(kt+1),s(kt+2) = 6 instr; need s(kt) -> vmcnt(4). stage(kt+3) after
// the barrier writes slot (kt-1)&3 whose readers drained before barrier(kt).
__global__ __launch_bounds__(256, 2) void k_gemm1(
    const u16* __restrict__ xn,   // [1024][4096] bf16
    const u16* __restrict__ w1t,  // [512][4096] bf16 (n-major)
    float* __restrict__ pp)       // [2][1024][512] f32 partials
{
  __shared__ __align__(16) u16 sA[4][64*32];
  __shared__ __align__(16) u16 sB[4][64*32];
  const int tid = threadIdx.x, lane = tid & 63, w = tid >> 6;
  const int n0 = blockIdx.x << 6, m0 = blockIdx.y << 6;
  const int ks = blockIdx.z;
  const int wm = w >> 1, wn = w & 1;
  const int rA = lane >> 2, cA = (lane & 3) << 3;
  const int fr = lane & 15, fq = lane >> 4;
  const f32x4 z4 = {0.f, 0.f, 0.f, 0.f};
  f32x4 acc[2][2];
  #pragma unroll
  for (int i=0;i<2;i++){ acc[i][0] = z4; acc[i][1] = z4; }

  auto stage = [&](int kt){
    const int b = kt & 3;
    const int kofs = (ks << 11) + (kt << 5) + cA;
    async16(sA[b] + w*512, xn  + (long)(m0 + w*16 + rA)*4096 + kofs);
    async16(sB[b] + w*512, w1t + (long)(n0 + w*16 + rA)*4096 + kofs);
  };

  stage(0); stage(1); stage(2);
  for (int kt = 0; kt < 64; ++kt){
    if (kt < 62)       asm volatile("s_waitcnt vmcnt(4)" ::: "memory");  // s(kt) done
    else if (kt == 62) asm volatile("s_waitcnt vmcnt(2)" ::: "memory");
    else               asm volatile("s_waitcnt vmcnt(0)" ::: "memory");
    __builtin_amdgcn_s_barrier();
    if (kt < 61) stage(kt + 3);
    const int b = kt & 3;
    bf16x8 af[2], bfv[2];
    #pragma unroll
    for (int i=0;i<2;i++) af[i]  = *(const bf16x8*)(sA[b] + ((wm<<5) + i*16 + fr)*32 + (fq<<3));
    #pragma unroll
    for (int j=0;j<2;j++) bfv[j] = *(const bf16x8*)(sB[b] + ((wn<<5) + j*16 + fr)*32 + (fq<<3));
    #pragma unroll
    for (int i=0;i<2;i++)
      #pragma unroll
      for (int j=0;j<2;j++)
        acc[i][j] = __builtin_amdgcn_mfma_f32_16x16x32_bf16(af[i], bfv[j], acc[i][j], 0, 0, 0);
  }
  float* po = pp + ((size_t)ks << 19);
  #pragma unroll
  for (int i=0;i<2;i++)
    #pragma unroll
    for (int j=0;j<2;j++)
      #pragma unroll
      for (int r=0;r<4;r++){
        const int row = m0 + (wm<<5) + i*16 + (fq<<2) + r;   // C/D: row=(lane>>4)*4+reg
        const int col = n0 + (wn<<5) + j*16 + fr;            //      col=lane&15
        po[row*512 + col] = acc[i][j][r];
      }
}

// ---- combine split-K partials: h = tanh(p0+p1+b1) -> bf16 ----
__global__ void k_gemm1b(const float* __restrict__ pp, const float* __restrict__ b1,
                         u16* __restrict__ hb){
  const int t = blockIdx.x * 256 + threadIdx.x;    // 131072 float4 groups
  const float4 a = ((const float4*)pp)[t];
  const float4 b = ((const float4*)pp)[131072 + t];
  const float4 bb = ((const float4*)b1)[t & 127];
  u16x4 o;
  o[0] = f32_to_bf16(fast_tanh(a.x + b.x + bb.x));
  o[1] = f32_to_bf16(fast_tanh(a.y + b.y + bb.y));
  o[2] = f32_to_bf16(fast_tanh(a.z + b.z + bb.z));
  o[3] = f32_to_bf16(fast_tanh(a.w + b.w + bb.w));
  ((u16x4*)hb)[t] = o;
}

// ---- GEMM2 + spline epilogue: M=1024 N=98304 K=512, tile 256x96 ----
// 1-D grid 4096, bijective XCD-chunked swizzle: work = ((id&7)<<9)|(id>>3).
// A single-buffer [256][32] + B 2-slot (2 x [128][32]); LDS 32768 B.
// Per kt:
//   vmcnt(0)            : A(kt) [flight = MFMA block ~ L2 lat, hmat L2-hot]
//                         and B(kt) [flight = full compute phase ~400-550cy,
//                         issued at bar1 of kt-1 -> covers L3/HBM] done
//   bar1                : all waves' data ready
//   stageB(kt+1)        : EARLY ISSUE into slot (kt+1)&1. Race-free: that
//                         slot's readers (iter kt-1) drained own lgkm before
//                         bar2(kt-1) < bar1(kt).
//   ds_read frags / lgkmcnt(0)+sched_barrier / bar2 (sA reusable)
//   stageA(kt+1) / sched_barrier / 24 MFMA
// No counted vmcnt anywhere -> minimal structure delta vs r9 (register guard:
// must stay <=88 arch VGPR; 92 costs 15us via the 30->21% occupancy cliff).
__global__ __launch_bounds__(256, 2) void k_gemm2(
    const u16* __restrict__ hmat,   // [1024][512] bf16
    const u16* __restrict__ w2t,    // [98304][512] bf16 (n-major)
    const float* __restrict__ b2,
    const float* __restrict__ x_in, // [1024][4096]
    const float* __restrict__ phase,
    float* __restrict__ phi_out,    // [1024][4096]
    float* __restrict__ ld)         // [1024] log-density accumulator (pre-init = ldin)
{
  __shared__ __align__(16) char smem[32768];
  u16* sA  = (u16*)smem;             // [256][32] bf16 (16384 B)
  u16* sB0 = (u16*)(smem + 16384);   // 2 slots x [128][32] bf16 (2 x 8192 B)
  float* sC = (float*)smem;          // [4 waves][16 rows][100] epilogue (25600 B, reuse)

  const int tid  = threadIdx.x;
  const int lane = tid & 63;
  const int w    = tid >> 6;
  const int id   = blockIdx.x;
  const int work = ((id & 7) << 9) | (id >> 3);   // bijective, 4096 = 8*512
  const int m0   = (work & 3) << 8;               // 0,256,512,768
  const int nt   = work >> 2;                     // 0..1023
  const long n0  = (long)nt * 96;

  const int rA = lane >> 2, cA = (lane & 3) << 3;
  const int fr = lane & 15, fq = lane >> 4;

  const f32x4 z4 = {0.f, 0.f, 0.f, 0.f};
  f32x4 acc[4][6];
  #pragma unroll
  for (int i=0;i<4;i++)
    #pragma unroll
    for (int j=0;j<6;j++) acc[i][j] = z4;

  auto stageA = [&](int kt){
    const int kofs = (kt << 5) + cA;
    #pragma unroll
    for (int cc = 0; cc < 4; ++cc){
      const int c = (w << 2) + cc;                         // 16 A chunks of 16 rows
      async16(sA + c*512, hmat + (long)(m0 + c*16 + rA)*512 + kofs);
    }
  };
  auto stageB = [&](int kt){
    u16* pB = sB0 + ((kt & 1) << 12);             // slot kt&1 (4096 u16)
    const int kofs = (kt << 5) + cA;
    #pragma unroll
    for (int cc = 0; cc < 2; ++cc){
      const int ch = (w << 1) + cc;                        // 8 B chunks (2 pad)
      int row = ch*16 + rA; if (row > 95) row = 95;        // clamp into valid rows
      async16(pB + ch*512, w2t + (n0 + row)*512 + kofs);
    }
  };

  stageB(0); stageA(0);
  for (int kt = 0; kt < 16; ++kt){
    asm volatile("s_waitcnt vmcnt(0)" ::: "memory");       // A(kt),B(kt) done
    __builtin_amdgcn_s_barrier();                          // bar1: all waves' data ready
    if (kt < 15) stageB(kt + 1);                           // EARLY issue, opposite slot
    const u16* bB = sB0 + ((kt & 1) << 12);
    bf16x8 af[4], bfv[6];
    #pragma unroll
    for (int i=0;i<4;i++)
      af[i] = *(const bf16x8*)(sA + ((w<<6) + i*16 + fr)*32 + (fq<<3));
    #pragma unroll
    for (int j=0;j<6;j++)
      bfv[j] = *(const bf16x8*)(bB + (j*16 + fr)*32 + (fq<<3));
    asm volatile("s_waitcnt lgkmcnt(0)" ::: "memory");     // own ds_reads landed
    __builtin_amdgcn_sched_barrier(0);                     // rule #18 fence
    __builtin_amdgcn_s_barrier();                          // bar2: sA reusable
    if (kt < 15) stageA(kt + 1);                           // A flies under MFMA
    __builtin_amdgcn_sched_barrier(0);                     // keep issue before MFMA
    #pragma unroll
    for (int i=0;i<4;i++)
      #pragma unroll
      for (int j=0;j<6;j++)
        acc[i][j] = __builtin_amdgcn_mfma_f32_16x16x32_bf16(af[i], bfv[j], acc[i][j], 0, 0, 0);
  }
  // kt=15: vmcnt(0) drained everything, no stage issued -> after bar2, sC reuse safe

  // ---- epilogue: RAW acc+b2 -> LDS -> per-(b,s_out) spline ----
  // myC regions are wave-private: no barriers needed inside (same-wave DS ops
  // are processed in order by the DS pipe; harness-verified across 12 rounds).
  // Three-pass register-diet spline (r9); phi staged in cols 96..99 ->
  // float4 coalesced stores; log-density via device atomics.
  const float shift = phase[0];
  float b2c[6];
  #pragma unroll
  for (int j=0;j<6;j++) b2c[j] = b2[n0 + j*16 + fr];
  float* myC = sC + w*1600;                                // 16 rows x 100 floats

  #pragma unroll
  for (int q = 0; q < 4; ++q){                             // quarter = row-frag index
    #pragma unroll
    for (int j=0;j<6;j++)
      #pragma unroll
      for (int r=0;r<4;r++)
        myC[((fq<<2)+r)*100 + j*16 + fr] = acc[q][j][r] + b2c[j];

    const int row = fr;                 // 0..15 within quarter
    const int g   = fq;                 // s_out group 0..3
    const float* tp = myC + row*100 + g*24;

    const int bg = m0 + (w<<6) + (q<<4) + row;
    const int s  = (nt<<2) + g;
    const float x = x_in[(long)bg*4096 + s];

    // pass 1: w_raw = tp[8..15]; sw (no array kept)
    const f32x4 w0 = *(const f32x4*)(tp + 8);
    const f32x4 w1 = *(const f32x4*)(tp + 12);
    float sw = 0.f;
    #pragma unroll
    for (int i=0;i<4;i++){ sw += exp_tanh(w0[i]); sw += exp_tanh(w1[i]); }

    // bin search in RAW cumsum space: cum_norm < x  <=>  cum_raw < x*sw/2pi
    const float xs = x * sw * (1.f / TWOPI_F);

    // pass 2: recompute ew, capture k / wkr / xkr by monotone overwrite
    float cw = 0.f, wkr = 0.f, xkr = 0.f; int k = 0;
    #pragma unroll
    for (int i=0;i<8;i++){
      const float e = exp_tanh(i < 4 ? w0[i] : w1[i-4]);
      if (cw < xs || i == 0){ k = i; wkr = e; xkr = cw; }
      cw += e;
    }

    // pass 3: h_raw = tp[0..7]; capture hkr / phr at i==k
    const f32x4 h0 = *(const f32x4*)(tp);
    const f32x4 h1 = *(const f32x4*)(tp + 4);
    float h2 = 0.f, hkr = 0.f, phr = 0.f;
    #pragma unroll
    for (int i=0;i<8;i++){
      const float e = exp_tanh(i < 4 ? h0[i] : h1[i-4]);
      if (i == k){ hkr = e; phr = h2; }
      h2 += e;
    }
    const float sh = h2;

    // only the 2 selected d values get tanh+softplus (runtime-indexed LDS read)
    const float* dp = tp + 16;
    const float th0 = tanh_nc(dp[k]);
    const float th1 = tanh_nc(dp[(k + 1) & 7]);
    const float dk  = __logf(1.f + __expf(th0));   // softplus, arg in (-1,1)
    const float dk1 = __logf(1.f + __expf(th1));

    const float rsh = rcpf(sh);
    const float rwk = rcpf(wkr);
    const float alpha = (xs - xkr) * rwk;          // == (x - x_{k-1})/w_k
    const float sk = hkr * rwk * (sw * rsh);       // == h_k/w_k
    const float hk = TWOPI_F * hkr * rsh;
    const float ph = TWOPI_F * phr * rsh;
    const float a1m = alpha * (1.f - alpha);
    const float denom = sk + (dk1 + dk - 2.f*sk)*a1m;
    const float rd = rcpf(denom);
    const float phiv = ph + hk*(sk*alpha*alpha + dk*a1m)*rd;
    float p = phiv + shift;                 // conditional subtract == mod
    if (p >= TWOPI_F) p -= TWOPI_F;
    if (p >= TWOPI_F) p -= TWOPI_F;
    myC[row*100 + 96 + g] = p;              // stage phi (cols 96..99 free)

    const float om = 1.f - alpha;
    const float num = dk1*alpha*alpha + 2.f*sk*a1m + dk*om*om;
    const float srd = sk * rd;
    float lg = __logf(srd*srd*num);         // == log(sk^2*num/denom^2)
    lg += __shfl_xor(lg, 16);               // sum over the 4 s_out groups (same row)
    lg += __shfl_xor(lg, 32);
    if (lane < 16){
      atomicAdd(ld + bg, -lg);              // device-scope, fire-and-forget
      const f32x4 pv = *(const f32x4*)(myC + lane*100 + 96);   // row = lane (==fr)
      const int bgr = m0 + (w<<6) + (q<<4) + lane;
      float4 o; o.x = pv[0]; o.y = pv[1]; o.z = pv[2]; o.w = pv[3];
      *(float4*)&phi_out[(long)bgr*4096 + (nt<<2)] = o;        // 16B coalesced
    }
  }
}

extern "C" void kernel_launch(void* const* d_in, const int* in_sizes, int n_in,
                              void* d_out, int out_size, void* d_ws, size_t ws_size,
                              hipStream_t stream){
  (void)in_sizes; (void)n_in; (void)out_size; (void)ws_size;
  const float* x_in  = (const float*)d_in[0];
  const float* x_pas = (const float*)d_in[1];
  const float* ldin  = (const float*)d_in[2];
  const float* w1    = (const float*)d_in[3];
  const float* b1    = (const float*)d_in[4];
  const float* w2    = (const float*)d_in[5];
  const float* b2    = (const float*)d_in[6];
  const float* phase = (const float*)d_in[7];
  float* out   = (float*)d_out;
  float* phi   = out;
  float* ldout = out + (size_t)1024*4096;

  // workspace layout (needs ~118.5 MB)
  char* ws = (char*)d_ws;
  float* stats = (float*)ws;                       // 8 B
  u16* xn   = (u16*)(ws + 256);                    // 8 MB   [1024][4096] bf16
  u16* w1t  = (u16*)(ws + 8388864);                // 4 MB   [512][4096] bf16
  u16* hb   = (u16*)(ws + 12583168);               // 1 MB   [1024][512] bf16
  u16* w2t  = (u16*)(ws + 13631744);               // 96 MB  [98304][512] bf16
  float* part = (float*)(ws + 114295040);          // 4 MB   gemm1 split-K partials

  hipMemsetAsync(stats, 0, 8, stream);
  k_stats<<<1024, 256, 0, stream>>>(x_pas, stats, ldin, ldout);
  k_prep<<<2048, 256, 0, stream>>>(x_pas, stats, xn);
  k_transpose_cvt<<<dim3(16, 4),  256, 0, stream>>>(w1, w1t, 4096, 512);
  k_transpose_cvt<<<dim3(2, 768), 256, 0, stream>>>(w2, w2t, 512, 98304);
  k_gemm1<<<dim3(8, 16, 2), 256, 0, stream>>>(xn, w1t, part);
  k_gemm1b<<<512, 256, 0, stream>>>(part, b1, hb);
  k_gemm2<<<dim3(4096), 256, 0, stream>>>(hb, w2t, b2, x_in, phase, phi, ldout);
}